// Round 11
// baseline (360.407 us; speedup 1.0000x reference)
//
#include <hip/hip_runtime.h>
#include <hip/hip_bf16.h>
#include <math.h>

typedef __attribute__((ext_vector_type(8))) short short8;
typedef __attribute__((ext_vector_type(4))) float f32x4;
typedef unsigned short u16;

#define L2E 1.44269504088896340736f

// ---------- helpers ----------
__device__ __forceinline__ u16 f2bf(float f) {
  union { float f; unsigned u; } x; x.f = f;
  unsigned r = x.u + 0x7fffu + ((x.u >> 16) & 1u);   // RNE
  return (u16)(r >> 16);
}

__device__ __forceinline__ void gload16(const void* g, void* l) {
  auto gp = reinterpret_cast<const __attribute__((address_space(1))) void*>(
      reinterpret_cast<uintptr_t>(g));
  auto lp = reinterpret_cast<__attribute__((address_space(3))) void*>(
      reinterpret_cast<uintptr_t>(l));
  __builtin_amdgcn_global_load_lds(gp, lp, 16, 0, 0);
}

// XCD-aware chunked remap (T1). Requires nwg % 8 == 0 (bijective).
__device__ __forceinline__ int xcd_swz(int flat, int nwg) {
  return (flat & 7) * (nwg >> 3) + (flat >> 3);
}

// exact T5 bucket: matches floor(2*log2(n/8)) with integer arithmetic
__device__ __forceinline__ int bucket_fn(int rel) {
  int n = -rel;              // i - j
  int ret = 0;
  if (n < 0) { ret = 16; n = -n; }
  if (n < 8) return ret + n;
  int e = 31 - __clz(n);
  unsigned nn = (unsigned)n * (unsigned)n;
  int f = 2 * e + ((nn >= (1u << (2 * e + 1))) ? 1 : 0) - 6;
  int val = 8 + f;
  if (val > 15) val = 15;
  return ret + val;
}

// ---------- fused prep ----------
__global__ __launch_bounds__(256) void prep(
    const float* __restrict__ wq, const float* __restrict__ wk,
    const float* __restrict__ wv, const float* __restrict__ fcw,
    const float* __restrict__ wi, const float* __restrict__ wo,
    const float* __restrict__ bq, const float* __restrict__ bk,
    const float* __restrict__ bv, const float* __restrict__ rel_bias,
    u16* __restrict__ wqb, u16* __restrict__ wkb, u16* __restrict__ wvb,
    u16* __restrict__ fcwb, u16* __restrict__ wib, u16* __restrict__ wob,
    float* __restrict__ fb, float* __restrict__ tab) {
  const int blk = blockIdx.x, t = threadIdx.x;
  if (blk < 12288) {
    const float* s; u16* d; int rel;
    if (blk < 1024)      { s = wq;  d = wqb;  rel = blk; }
    else if (blk < 2048) { s = wk;  d = wkb;  rel = blk - 1024; }
    else if (blk < 3072) { s = wv;  d = wvb;  rel = blk - 2048; }
    else if (blk < 4096) { s = fcw; d = fcwb; rel = blk - 3072; }
    else if (blk < 8192) { s = wi;  d = wib;  rel = blk - 4096; }
    else                 { s = wo;  d = wob;  rel = blk - 8192; }
    const int i = (rel * 256 + t) * 4;
    float4 v = *(const float4*)&s[i];
    d[i + 0] = f2bf(v.x); d[i + 1] = f2bf(v.y);
    d[i + 2] = f2bf(v.z); d[i + 3] = f2bf(v.w);
  } else if (blk < 12300) {
    const int i = (blk - 12288) * 256 + t;   // 3072
    fb[i] = i < 1024 ? bq[i] : (i < 2048 ? bk[i - 1024] : bv[i - 2048]);
  } else {
    const int idx = (blk - 12300) * 256 + t; // 16*2048
    const int h = idx >> 11;
    const int rel = (idx & 2047) - 1024;
    tab[idx] = rel_bias[bucket_fn(rel) * 16 + h];
  }
}

__global__ __launch_bounds__(256) void write_pb(const float* __restrict__ tab,
                                                float* __restrict__ pb) {
  const int i = blockIdx.x, h = blockIdx.y, t = threadIdx.x;
  __shared__ float tabs[2048];
  ((float4*)tabs)[t]       = ((const float4*)(tab + h * 2048))[t];
  ((float4*)tabs)[t + 256] = ((const float4*)(tab + h * 2048))[t + 256];
  __syncthreads();
  const int j = t * 4;
  float4 o;
  o.x = tabs[j + 0 - i + 1024];
  o.y = tabs[j + 1 - i + 1024];
  o.z = tabs[j + 2 - i + 1024];
  o.w = tabs[j + 3 - i + 1024];
#pragma unroll
  for (int b = 0; b < 4; b++)
    *(float4*)&pb[(((size_t)(b * 16 + h)) * 1024 + i) * 1024 + j] = o;
}

__global__ __launch_bounds__(256) void t5_ln(const float* __restrict__ x,
                                             const float* __restrict__ wgt,
                                             float eps, u16* __restrict__ out) {
  const int row = blockIdx.x, t = threadIdx.x;
  const float4 v = ((const float4*)(x + (size_t)row * 1024))[t];
  float ss = v.x * v.x + v.y * v.y + v.z * v.z + v.w * v.w;
#pragma unroll
  for (int off = 1; off < 64; off <<= 1) ss += __shfl_xor(ss, off, 64);
  __shared__ float red[4];
  if ((t & 63) == 0) red[t >> 6] = ss;
  __syncthreads();
  float tot = red[0] + red[1] + red[2] + red[3];
  float inv = 1.0f / sqrtf(tot * (1.0f / 1024.0f) + eps);
  const float4 wv = ((const float4*)wgt)[t];
  u16* o = out + (size_t)row * 1024 + t * 4;
  o[0] = f2bf(v.x * inv * wv.x);
  o[1] = f2bf(v.y * inv * wv.y);
  o[2] = f2bf(v.z * inv * wv.z);
  o[3] = f2bf(v.w * inv * wv.w);
}

__global__ __launch_bounds__(256) void transpose_v(const u16* __restrict__ v,
                                                   u16* __restrict__ vt) {
  __shared__ u16 T[64][72];
  const int bh = blockIdx.y;
  const int l0 = blockIdx.x * 64;
  const int t = threadIdx.x;
  const int sr = t >> 3, sc = (t & 7) * 8;
  const u16* vb = v + (size_t)bh * 65536;
  *(short8*)&T[sr][sc]      = *(const short8*)&vb[(size_t)(l0 + sr) * 64 + sc];
  *(short8*)&T[sr + 32][sc] = *(const short8*)&vb[(size_t)(l0 + sr + 32) * 64 + sc];
  __syncthreads();
  u16* vtb = vt + (size_t)bh * 65536;
  short8 o0, o1;
#pragma unroll
  for (int u = 0; u < 8; u++) {
    ((u16*)&o0)[u] = T[sc + u][sr];
    ((u16*)&o1)[u] = T[sc + u][sr + 32];
  }
  *(short8*)&vtb[(size_t)sr * 1024 + l0 + sc]        = o0;
  *(short8*)&vtb[(size_t)(sr + 32) * 1024 + l0 + sc] = o1;
}

// ---------- GEMM 128x128: bf16 out via LDS epilogue + XCD swizzle ----------
// MODE 0: (acc+fb[col])*sel_scale -> bf16 permuted [b,h,pos,dk], QKV fused (N=3072)
// MODE 2: gelu(acc) -> bf16 row-major
template<int MODE>
__global__ __launch_bounds__(256, 3) void gemm_nt(
    const u16* __restrict__ A, const u16* __restrict__ Bw,
    int M, int N, int K,
    const float* __restrict__ bias, const float* __restrict__ res,
    float scale, float* __restrict__ outF, u16* __restrict__ outB) {
  __shared__ u16 As[3][4096];
  __shared__ u16 Bs[3][4096];
  const int t = threadIdx.x;
  const int w = t >> 6, lane = t & 63;
  const int wr = w >> 1, wc = w & 1;
  const int g = lane >> 4, lc = lane & 15;

  const int nwg = gridDim.x * gridDim.y;
  const int flat = xcd_swz(blockIdx.y * gridDim.x + blockIdx.x, nwg);
  const int bx = flat % gridDim.x, by = flat / gridDim.x;
  const int m0 = by * 128, n0 = bx * 128;

  const int srow = w * 16 + (lane >> 2);
  const int sc8  = (lane & 3) ^ ((srow >> 1) & 3);
  const u16* Ag = &A[(size_t)(m0 + srow) * K + sc8 * 8];
  const u16* Bg = &Bw[(size_t)(n0 + srow) * K + sc8 * 8];
  const size_t row64 = (size_t)64 * K;
  const int swz = (lc >> 1) & 3;

  const int NT = K >> 5;
  f32x4 acc[4][4] = {};

  auto stage = [&](int buf, int tt) {
    const int k0 = tt << 5;
    u16* lA = &As[buf][w * 512];
    u16* lB = &Bs[buf][w * 512];
    gload16(Ag + k0, lA);
    gload16(Ag + row64 + k0, lA + 2048);
    gload16(Bg + k0, lB);
    gload16(Bg + row64 + k0, lB + 2048);
  };

  stage(0, 0);
  stage(1, 1);

  for (int tt = 0; tt < NT; tt++) {
    const int cur = tt % 3;
    if (tt < NT - 1) {
      asm volatile("s_waitcnt vmcnt(4)" ::: "memory");
    } else {
      asm volatile("s_waitcnt vmcnt(0)" ::: "memory");
    }
    __builtin_amdgcn_s_barrier();
    short8 af[4], bf[4];
#pragma unroll
    for (int mi = 0; mi < 4; mi++)
      af[mi] = *(short8*)&As[cur][(wr * 64 + mi * 16 + lc) * 32 + (g ^ swz) * 8];
#pragma unroll
    for (int ni = 0; ni < 4; ni++)
      bf[ni] = *(short8*)&Bs[cur][(wc * 64 + ni * 16 + lc) * 32 + (g ^ swz) * 8];
    if (tt + 2 < NT) stage((tt + 2) % 3, tt + 2);
#pragma unroll
    for (int mi = 0; mi < 4; mi++)
#pragma unroll
      for (int ni = 0; ni < 4; ni++)
        acc[mi][ni] = __builtin_amdgcn_mfma_f32_16x16x32_bf16(af[mi], bf[ni], acc[mi][ni], 0, 0, 0);
  }

  // ---- epilogue: per-mi re-layout through LDS -> coalesced 16B stores ----
  u16* Es = &As[0][0];
  __syncthreads();
#pragma unroll
  for (int mi = 0; mi < 4; mi++) {
#pragma unroll
    for (int ni = 0; ni < 4; ni++) {
#pragma unroll
      for (int r = 0; r < 4; r++) {
        const int col = n0 + wc * 64 + ni * 16 + lc;
        float v = acc[mi][ni][r];
        if (MODE == 0) {
          v = (v + bias[col]) * ((col >> 10) == 0 ? scale : 1.0f);
        } else {
          v = 0.5f * v * (1.0f + erff(v * 0.70710678118654752440f));
        }
        Es[wr * 2048 + (g * 4 + r) * 128 + wc * 64 + ni * 16 + lc] = f2bf(v);
      }
    }
    __syncthreads();
    {
      const int rr = t >> 3;
      const int wr2 = rr >> 4, r16 = rr & 15;
      const int cc = (t & 7) * 16;
      short8 o0 = *(short8*)&Es[wr2 * 2048 + r16 * 128 + cc];
      short8 o1 = *(short8*)&Es[wr2 * 2048 + r16 * 128 + cc + 8];
      const int row = m0 + wr2 * 64 + mi * 16 + r16;
      if (MODE == 0) {
        const int col0 = n0 + cc;
        const int which = col0 >> 10, c = col0 & 1023;
        const int hh = c >> 6, dk = c & 63;
        const int b = row >> 10, pos = row & 1023;
        u16* dst = outB + (size_t)which * 4194304 +
                   (((size_t)(b * 16 + hh)) * 1024 + pos) * 64 + dk;
        *(short8*)dst = o0;
        *(short8*)(dst + 8) = o1;
      } else {
        u16* dst = outB + (size_t)row * (size_t)N + n0 + cc;
        *(short8*)dst = o0;
        *(short8*)(dst + 8) = o1;
      }
    }
    __syncthreads();
  }
}

// ---------- GEMM 256x256: 8 waves (2x4), wave-tile 128x64, same sync skeleton ----------
// FFN1 only: gelu(acc) -> bf16 row-major. Grid 16x16 = 256 blocks = 1/CU, no tail.
__global__ __launch_bounds__(512, 2) void gemm256_gelu(
    const u16* __restrict__ A, const u16* __restrict__ Bw,
    int M, int N, int K, u16* __restrict__ outB) {
  __shared__ u16 As[3][8192];   // [buf][256 rows][32]
  __shared__ u16 Bs[3][8192];
  const int t = threadIdx.x;            // 0..511
  const int w = t >> 6, lane = t & 63;  // 8 waves
  const int wrm = w >> 2, wcn = w & 3;  // 2 (M) x 4 (N)
  const int g = lane >> 4, lc = lane & 15;

  const int nwg = gridDim.x * gridDim.y;
  const int flat = xcd_swz(blockIdx.y * gridDim.x + blockIdx.x, nwg);
  const int bx = flat % gridDim.x, by = flat / gridDim.x;
  const int m0 = by * 256, n0 = bx * 256;

  // staging: 2 issues each for A and B; issue0 rows 0..127, issue1 rows 128..255.
  // (srow+128)>>1 & 3 == (srow>>1)&3, so one pre-swizzled chunk works for both.
  const int srow = w * 16 + (lane >> 2);
  const int sc8  = (lane & 3) ^ ((srow >> 1) & 3);
  const u16* Ag = &A[(size_t)(m0 + srow) * K + sc8 * 8];
  const u16* Bg = &Bw[(size_t)(n0 + srow) * K + sc8 * 8];
  const size_t row128 = (size_t)128 * K;
  const int swz = (lc >> 1) & 3;

  const int NT = K >> 5;
  f32x4 acc[8][4] = {};

  auto stage = [&](int buf, int tt) {
    const int k0 = tt << 5;
    u16* lA = &As[buf][w * 512];
    u16* lB = &Bs[buf][w * 512];
    gload16(Ag + k0, lA);
    gload16(Ag + row128 + k0, lA + 4096);
    gload16(Bg + k0, lB);
    gload16(Bg + row128 + k0, lB + 4096);
  };

  stage(0, 0);
  stage(1, 1);

  for (int tt = 0; tt < NT; tt++) {
    const int cur = tt % 3;
    if (tt < NT - 1) {
      asm volatile("s_waitcnt vmcnt(4)" ::: "memory");
    } else {
      asm volatile("s_waitcnt vmcnt(0)" ::: "memory");
    }
    __builtin_amdgcn_s_barrier();
    short8 af[8], bf[4];
#pragma unroll
    for (int mi = 0; mi < 8; mi++)
      af[mi] = *(short8*)&As[cur][(wrm * 128 + mi * 16 + lc) * 32 + (g ^ swz) * 8];
#pragma unroll
    for (int ni = 0; ni < 4; ni++)
      bf[ni] = *(short8*)&Bs[cur][(wcn * 64 + ni * 16 + lc) * 32 + (g ^ swz) * 8];
    if (tt + 2 < NT) stage((tt + 2) % 3, tt + 2);
    __builtin_amdgcn_s_setprio(1);
#pragma unroll
    for (int mi = 0; mi < 8; mi++)
#pragma unroll
      for (int ni = 0; ni < 4; ni++)
        acc[mi][ni] = __builtin_amdgcn_mfma_f32_16x16x32_bf16(af[mi], bf[ni], acc[mi][ni], 0, 0, 0);
    __builtin_amdgcn_s_setprio(0);
  }

  // ---- epilogue: per-mi re-layout through LDS (Es[2][16][256]) -> 16B stores ----
  u16* Es = &As[0][0];   // 16 KB
  __syncthreads();
#pragma unroll
  for (int mi = 0; mi < 8; mi++) {
#pragma unroll
    for (int ni = 0; ni < 4; ni++) {
#pragma unroll
      for (int r = 0; r < 4; r++) {
        float v = acc[mi][ni][r];
        v = 0.5f * v * (1.0f + erff(v * 0.70710678118654752440f));
        Es[(wrm * 16 + g * 4 + r) * 256 + wcn * 64 + ni * 16 + lc] = f2bf(v);
      }
    }
    __syncthreads();
    {
      const int rr = t >> 4;               // 0..31
      const int wr2 = rr >> 4, r16 = rr & 15;
      const int cc = (t & 15) * 16;
      short8 o0 = *(short8*)&Es[(wr2 * 16 + r16) * 256 + cc];
      short8 o1 = *(short8*)&Es[(wr2 * 16 + r16) * 256 + cc + 8];
      const int row = m0 + wr2 * 128 + mi * 16 + r16;
      u16* dst = outB + (size_t)row * (size_t)N + n0 + cc;
      *(short8*)dst = o0;
      *(short8*)(dst + 8) = o1;
    }
    __syncthreads();
  }
}

// ---------- GEMM 64x128 tile (FC / FFN2: 512 blocks = 2/CU) + XCD swizzle ----------
template<int MODE>
__global__ __launch_bounds__(256, 4) void gemm_nt64(
    const u16* __restrict__ A, const u16* __restrict__ Bw,
    int M, int N, int K,
    const float* __restrict__ bias, const float* __restrict__ res,
    float* __restrict__ outF) {
  __shared__ u16 As[3][2048];
  __shared__ u16 Bs[3][4096];
  const int t = threadIdx.x;
  const int w = t >> 6, lane = t & 63;
  const int wr = w >> 1, wc = w & 1;
  const int g = lane >> 4, lc = lane & 15;

  const int nwg = gridDim.x * gridDim.y;
  const int flat = xcd_swz(blockIdx.y * gridDim.x + blockIdx.x, nwg);
  const int bx = flat % gridDim.x, by = flat / gridDim.x;
  const int m0 = by * 64, n0 = bx * 128;

  const int srow = w * 16 + (lane >> 2);
  const int sc8  = (lane & 3) ^ ((srow >> 1) & 3);
  const u16* Ag = &A[(size_t)(m0 + srow) * K + sc8 * 8];
  const u16* Bg = &Bw[(size_t)(n0 + srow) * K + sc8 * 8];
  const size_t row64 = (size_t)64 * K;
  const int swz = (lc >> 1) & 3;

  const int NT = K >> 5;
  f32x4 acc[2][4] = {};

  auto stage = [&](int buf, int tt) {
    const int k0 = tt << 5;
    gload16(Ag + k0, &As[buf][w * 512]);
    gload16(Bg + k0, &Bs[buf][w * 512]);
    gload16(Bg + row64 + k0, &Bs[buf][w * 512 + 2048]);
  };

  stage(0, 0);
  stage(1, 1);

  for (int tt = 0; tt < NT; tt++) {
    const int cur = tt % 3;
    if (tt < NT - 1) {
      asm volatile("s_waitcnt vmcnt(3)" ::: "memory");
    } else {
      asm volatile("s_waitcnt vmcnt(0)" ::: "memory");
    }
    __builtin_amdgcn_s_barrier();
    short8 af[2], bf[4];
#pragma unroll
    for (int mi = 0; mi < 2; mi++)
      af[mi] = *(short8*)&As[cur][(wr * 32 + mi * 16 + lc) * 32 + (g ^ swz) * 8];
#pragma unroll
    for (int ni = 0; ni < 4; ni++)
      bf[ni] = *(short8*)&Bs[cur][(wc * 64 + ni * 16 + lc) * 32 + (g ^ swz) * 8];
    if (tt + 2 < NT) stage((tt + 2) % 3, tt + 2);
#pragma unroll
    for (int mi = 0; mi < 2; mi++)
#pragma unroll
      for (int ni = 0; ni < 4; ni++)
        acc[mi][ni] = __builtin_amdgcn_mfma_f32_16x16x32_bf16(af[mi], bf[ni], acc[mi][ni], 0, 0, 0);
  }

#pragma unroll
  for (int mi = 0; mi < 2; mi++) {
#pragma unroll
    for (int ni = 0; ni < 4; ni++) {
#pragma unroll
      for (int r = 0; r < 4; r++) {
        const int row = m0 + wr * 32 + mi * 16 + g * 4 + r;
        const int col = n0 + wc * 64 + ni * 16 + lc;
        float v = acc[mi][ni][r];
        if (MODE == 1) {
          v += bias[col] + res[(size_t)row * 1024 + col];
        } else {
          v += res[(size_t)row * 1024 + col];
        }
        outF[(size_t)row * 1024 + col] = v;
      }
    }
  }
}

// ---------- flash attention: ctx + (m,l), exp2 domain, XCD swizzle ----------
__global__ __launch_bounds__(256) void attn_kernel(
    const u16* __restrict__ q, const u16* __restrict__ k,
    const u16* __restrict__ vt, const float* __restrict__ tab,
    u16* __restrict__ ctx, float* __restrict__ ml) {
  const int flat = xcd_swz(blockIdx.y * 16 + blockIdx.x, 1024);
  const int bh = flat / 16;
  const int i0 = (flat % 16) * 64;
  const int h = bh & 15, b = bh >> 4;
  const int t = threadIdx.x, w = t >> 6, lane = t & 63;
  const int g = lane >> 4, lc = lane & 15;
  const int sr = t >> 3;
  const int swc = ((t & 7) ^ (sr & 7)) * 8;
  const int sc = (t & 7) * 8;

  __shared__ u16 Ks[2][64][64];
  __shared__ u16 Vts[2][64][64];
  __shared__ u16 P[4][16][64];
  __shared__ float tabs[2048];

  const u16* qb  = q + (size_t)bh * 65536;
  const u16* kb  = k + (size_t)bh * 65536;
  const u16* vtb = vt + (size_t)bh * 65536;

  {
    float4 t0 = ((const float4*)(tab + h * 2048))[t];
    float4 t1 = ((const float4*)(tab + h * 2048))[t + 256];
    t0.x *= L2E; t0.y *= L2E; t0.z *= L2E; t0.w *= L2E;
    t1.x *= L2E; t1.y *= L2E; t1.z *= L2E; t1.w *= L2E;
    ((float4*)tabs)[t]       = t0;
    ((float4*)tabs)[t + 256] = t1;
  }

  const short8 aq0 = *(const short8*)&qb[(size_t)(i0 + w * 16 + lc) * 64 + g * 8];
  const short8 aq1 = *(const short8*)&qb[(size_t)(i0 + w * 16 + lc) * 64 + 32 + g * 8];

  {
    short8 ka = *(const short8*)&kb[(size_t)sr * 64 + sc];
    short8 kc = *(const short8*)&kb[(size_t)(sr + 32) * 64 + sc];
    short8 va = *(const short8*)&vtb[(size_t)sr * 1024 + sc];
    short8 vc = *(const short8*)&vtb[(size_t)(sr + 32) * 1024 + sc];
    *(short8*)&Ks[0][sr][swc]       = ka;
    *(short8*)&Ks[0][sr + 32][swc]  = kc;
    *(short8*)&Vts[0][sr][swc]      = va;
    *(short8*)&Vts[0][sr + 32][swc] = vc;
  }
  __syncthreads();

  const int rx = lc & 7;
  const int ibase = 1024 - i0 - (w * 16 + g * 4) + lc;

  float m_r[4] = {-INFINITY, -INFINITY, -INFINITY, -INFINITY};
  float l_r[4] = {0.f, 0.f, 0.f, 0.f};
  f32x4 cacc[4] = {};

  for (int tt = 0; tt < 16; tt++) {
    const int buf = tt & 1;
    const int j0 = tt * 64;

    short8 nka, nkc, nva, nvc;
    if (tt < 15) {
      const int jn = j0 + 64;
      nka = *(const short8*)&kb[(size_t)(jn + sr) * 64 + sc];
      nkc = *(const short8*)&kb[(size_t)(jn + sr + 32) * 64 + sc];
      nva = *(const short8*)&vtb[(size_t)sr * 1024 + jn + sc];
      nvc = *(const short8*)&vtb[(size_t)(sr + 32) * 1024 + jn + sc];
    }

    f32x4 s[4] = {};
#pragma unroll
    for (int ni = 0; ni < 4; ni++) {
      short8 b0 = *(short8*)&Ks[buf][ni * 16 + lc][(g ^ rx) * 8];
      short8 b1 = *(short8*)&Ks[buf][ni * 16 + lc][((4 + g) ^ rx) * 8];
      s[ni] = __builtin_amdgcn_mfma_f32_16x16x32_bf16(aq0, b0, s[ni], 0, 0, 0);
      s[ni] = __builtin_amdgcn_mfma_f32_16x16x32_bf16(aq1, b1, s[ni], 0, 0, 0);
    }
#pragma unroll
    for (int ni = 0; ni < 4; ni++)
#pragma unroll
      for (int r = 0; r < 4; r++)
        s[ni][r] += tabs[ibase + j0 + ni * 16 - r];

#pragma unroll
    for (int r = 0; r < 4; r++) {
      float tm = fmaxf(fmaxf(s[0][r], s[1][r]), fmaxf(s[2][r], s[3][r]));
#pragma unroll
      for (int off = 1; off < 16; off <<= 1) tm = fmaxf(tm, __shfl_xor(tm, off, 64));
      const float mn = fmaxf(m_r[r], tm);
      const float scl = __builtin_amdgcn_exp2f(m_r[r] - mn);
      float rs = 0.f;
#pragma unroll
      for (int ni = 0; ni < 4; ni++) {
        float p = __builtin_amdgcn_exp2f(s[ni][r] - mn);
        s[ni][r] = p;
        rs += p;
      }
#pragma unroll
      for (int off = 1; off < 16; off <<= 1) rs += __shfl_xor(rs, off, 64);
      l_r[r] = l_r[r] * scl + rs;
      m_r[r] = mn;
#pragma unroll
      for (int d = 0; d < 4; d++) cacc[d][r] *= scl;
    }

#pragma unroll
    for (int ni = 0; ni < 4; ni++)
#pragma unroll
      for (int r = 0; r < 4; r++) {
        const int prow = g * 4 + r;
        P[w][prow][(((ni * 2 + (lc >> 3)) ^ (prow & 7)) << 3) | (lc & 7)] = f2bf(s[ni][r]);
      }

    short8 ap0 = *(short8*)&P[w][lc][(g ^ rx) * 8];
    short8 ap1 = *(short8*)&P[w][lc][((4 + g) ^ rx) * 8];
#pragma unroll
    for (int d = 0; d < 4; d++) {
      short8 bv0 = *(short8*)&Vts[buf][d * 16 + lc][(g ^ rx) * 8];
      short8 bv1 = *(short8*)&Vts[buf][d * 16 + lc][((4 + g) ^ rx) * 8];
      cacc[d] = __builtin_amdgcn_mfma_f32_16x16x32_bf16(ap0, bv0, cacc[d], 0, 0, 0);
      cacc[d] = __builtin_amdgcn_mfma_f32_16x16x32_bf16(ap1, bv1, cacc[d], 0, 0, 0);
    }

    if (tt < 15) {
      *(short8*)&Ks[buf ^ 1][sr][swc]       = nka;
      *(short8*)&Ks[buf ^ 1][sr + 32][swc]  = nkc;
      *(short8*)&Vts[buf ^ 1][sr][swc]      = nva;
      *(short8*)&Vts[buf ^ 1][sr + 32][swc] = nvc;
    }
    __syncthreads();
  }

  float inv[4];
#pragma unroll
  for (int r = 0; r < 4; r++) inv[r] = 1.0f / l_r[r];
#pragma unroll
  for (int d = 0; d < 4; d++)
#pragma unroll
    for (int r = 0; r < 4; r++) {
      const int pos = i0 + w * 16 + g * 4 + r;
      ctx[((size_t)b * 1024 + pos) * 1024 + h * 64 + d * 16 + lc] = f2bf(cacc[d][r] * inv[r]);
    }
  if (lc == 0) {
#pragma unroll
    for (int r = 0; r < 4; r++) {
      const int i = i0 + w * 16 + g * 4 + r;
      ml[(size_t)bh * 1024 + i] = m_r[r];
      ml[65536 + (size_t)bh * 1024 + i] = l_r[r];
    }
  }
}

// ---------- attn_sum: recompute scores (exp2 domain), sum over heads ----------
__global__ __launch_bounds__(256) void attn_sum_kernel(
    const u16* __restrict__ q, const u16* __restrict__ k,
    const float* __restrict__ tab, const float* __restrict__ ml,
    float* __restrict__ asum) {
  const int flat = xcd_swz(((blockIdx.z * 16 + blockIdx.y) * 16) + blockIdx.x, 1024);
  const int j0 = (flat % 16) * 64;
  const int i0 = ((flat / 16) % 16) * 64;
  const int b = flat / 256;
  const int t = threadIdx.x, w = t >> 6, lane = t & 63;
  const int g = lane >> 4, lc = lane & 15;
  const int sr = t >> 3;
  const int swc = ((t & 7) ^ (sr & 7)) * 8;
  const int sc = (t & 7) * 8;
  const int rx = lc & 7;
  __shared__ u16 Ks[64][64];
  __shared__ float tabs[128];

  f32x4 acc[4] = {};

  for (int h = 0; h < 16; h++) {
    const int bh = b * 16 + h;
    __syncthreads();
    const u16* kb = k + (size_t)bh * 65536;
    *(short8*)&Ks[sr][swc]      = *(const short8*)&kb[(size_t)(j0 + sr) * 64 + sc];
    *(short8*)&Ks[sr + 32][swc] = *(const short8*)&kb[(size_t)(j0 + sr + 32) * 64 + sc];
    if (t < 127) tabs[t] = tab[h * 2048 + (j0 - i0 - 63 + t) + 1024] * L2E;
    __syncthreads();
    const u16* qb = q + (size_t)bh * 65536;
    short8 aq0 = *(const short8*)&qb[(size_t)(i0 + w * 16 + lc) * 64 + g * 8];
    short8 aq1 = *(const short8*)&qb[(size_t)(i0 + w * 16 + lc) * 64 + 32 + g * 8];
    f32x4 s[4] = {};
#pragma unroll
    for (int ni = 0; ni < 4; ni++) {
      short8 b0 = *(short8*)&Ks[ni * 16 + lc][(g ^ rx) * 8];
      short8 b1 = *(short8*)&Ks[ni * 16 + lc][((4 + g) ^ rx) * 8];
      s[ni] = __builtin_amdgcn_mfma_f32_16x16x32_bf16(aq0, b0, s[ni], 0, 0, 0);
      s[ni] = __builtin_amdgcn_mfma_f32_16x16x32_bf16(aq1, b1, s[ni], 0, 0, 0);
    }
    float mm[4], li[4];
#pragma unroll
    for (int r = 0; r < 4; r++) {
      const int i = i0 + w * 16 + g * 4 + r;
      mm[r] = ml[(size_t)bh * 1024 + i];
      li[r] = 1.0f / ml[65536 + (size_t)bh * 1024 + i];
    }
#pragma unroll
    for (int ni = 0; ni < 4; ni++)
#pragma unroll
      for (int r = 0; r < 4; r++) {
        float sv = s[ni][r] + tabs[ni * 16 + lc - w * 16 - g * 4 - r + 63];
        acc[ni][r] += __builtin_amdgcn_exp2f(sv - mm[r]) * li[r];
      }
  }
#pragma unroll
  for (int ni = 0; ni < 4; ni++)
#pragma unroll
    for (int r = 0; r < 4; r++) {
      const int i = i0 + w * 16 + g * 4 + r;
      asum[((size_t)b * 1024 + i) * 1024 + j0 + ni * 16 + lc] = acc[ni][r];
    }
}

// ---------- launch ----------
extern "C" void kernel_launch(void* const* d_in, const int* in_sizes, int n_in,
                              void* d_out, int out_size, void* d_ws, size_t ws_size,
                              hipStream_t stream) {
  const float* src      = (const float*)d_in[0];
  const float* ln1_w    = (const float*)d_in[2];
  const float* wq       = (const float*)d_in[3];
  const float* bq       = (const float*)d_in[4];
  const float* wk       = (const float*)d_in[5];
  const float* bk       = (const float*)d_in[6];
  const float* wv       = (const float*)d_in[7];
  const float* bv       = (const float*)d_in[8];
  const float* fc_w     = (const float*)d_in[9];
  const float* fc_b     = (const float*)d_in[10];
  const float* rel_bias = (const float*)d_in[11];
  const float* ln2_w    = (const float*)d_in[12];
  const float* wi       = (const float*)d_in[13];
  const float* wo       = (const float*)d_in[14];

  const size_t MB = 1u << 20;
  char* ws = (char*)d_ws;
  u16* wq_b   = (u16*)(ws + 0 * MB);     // wq/wk/wv contiguous = fused [3072][1024]
  u16* wk_b   = (u16*)(ws + 2 * MB);
  u16* wv_b   = (u16*)(ws + 4 * MB);
  u16* fcw_b  = (u16*)(ws + 6 * MB);
  u16* wi_b   = (u16*)(ws + 8 * MB);
  u16* wo_b   = (u16*)(ws + 16 * MB);
  u16* proj_b = (u16*)(ws + 24 * MB);   // reused as nx
  u16* q_b    = (u16*)(ws + 32 * MB);   // q/k/v contiguous, 4M u16 apart
  u16* k_b    = (u16*)(ws + 40 * MB);
  u16* v_b    = (u16*)(ws + 48 * MB);
  u16* vt_b   = (u16*)(ws + 56 * MB);
  u16* h_b    = (u16*)(ws + 32 * MB);   // aliases q/k/v/vt (dead by then)
  u16* ctx_b  = (u16*)(ws + 64 * MB);
  float* attn_out = (float*)(ws + 72 * MB);
  float* ml   = (float*)(ws + 88 * MB);
  float* tab  = (float*)(ws + 88 * MB + 512 * 1024);
  float* fb   = (float*)(ws + 90 * MB);

  float* outF = (float*)d_out;
  float* asum = outF + 4194304;
  float* pb   = outF + 8388608;

  prep<<<12428, 256, 0, stream>>>(wq, wk, wv, fc_w, wi, wo, bq, bk, bv, rel_bias,
                                  wq_b, wk_b, wv_b, fcw_b, wi_b, wo_b, fb, tab);

  write_pb<<<dim3(1024, 16), 256, 0, stream>>>(tab, pb);

  t5_ln<<<4096, 256, 0, stream>>>(src, ln1_w, 1e-12f, proj_b);

  // fused QKV: 128x128 tiles, 768 blocks = exactly 3 rounds at 3/CU
  gemm_nt<0><<<dim3(24, 32), 256, 0, stream>>>(proj_b, wq_b, 4096, 3072, 1024, fb, nullptr,
                                               0.125f * L2E, nullptr, q_b);

  transpose_v<<<dim3(16, 64), 256, 0, stream>>>(v_b, vt_b);
  attn_kernel<<<dim3(16, 64), 256, 0, stream>>>(q_b, k_b, vt_b, tab, ctx_b, ml);
  attn_sum_kernel<<<dim3(16, 16, 4), 256, 0, stream>>>(q_b, k_b, tab, ml, asum);

  // FC: 64x128 tile -> 512 blocks = 2/CU
  gemm_nt64<1><<<dim3(8, 64), 256, 0, stream>>>(ctx_b, fcw_b, 4096, 1024, 1024, fc_b, src, attn_out);

  t5_ln<<<4096, 256, 0, stream>>>(attn_out, ln2_w, 1e-6f, proj_b);

  // FFN1: 256x256 tiles, 8 waves, grid 16x16 = 256 blocks = 1/CU exact
  gemm256_gelu<<<dim3(16, 16), 512, 0, stream>>>(proj_b, wi_b, 4096, 4096, 1024, h_b);
  // FFN2: 64x128 tile -> 512 blocks = 2/CU
  gemm_nt64<3><<<dim3(8, 64), 256, 0, stream>>>(h_b, wo_b, 4096, 1024, 4096, nullptr, attn_out, outF);
}

// Round 12
// 351.821 us; speedup vs baseline: 1.0244x; 1.0244x over previous
//
#include <hip/hip_runtime.h>
#include <hip/hip_bf16.h>
#include <math.h>

typedef __attribute__((ext_vector_type(8))) short short8;
typedef __attribute__((ext_vector_type(4))) float f32x4;
typedef unsigned short u16;

#define L2E 1.44269504088896340736f

// ---------- helpers ----------
__device__ __forceinline__ u16 f2bf(float f) {
  union { float f; unsigned u; } x; x.f = f;
  unsigned r = x.u + 0x7fffu + ((x.u >> 16) & 1u);   // RNE
  return (u16)(r >> 16);
}

__device__ __forceinline__ void gload16(const void* g, void* l) {
  auto gp = reinterpret_cast<const __attribute__((address_space(1))) void*>(
      reinterpret_cast<uintptr_t>(g));
  auto lp = reinterpret_cast<__attribute__((address_space(3))) void*>(
      reinterpret_cast<uintptr_t>(l));
  __builtin_amdgcn_global_load_lds(gp, lp, 16, 0, 0);
}

// XCD-aware chunked remap (T1). Requires nwg % 8 == 0 (bijective).
__device__ __forceinline__ int xcd_swz(int flat, int nwg) {
  return (flat & 7) * (nwg >> 3) + (flat >> 3);
}

// exact T5 bucket: matches floor(2*log2(n/8)) with integer arithmetic
__device__ __forceinline__ int bucket_fn(int rel) {
  int n = -rel;              // i - j
  int ret = 0;
  if (n < 0) { ret = 16; n = -n; }
  if (n < 8) return ret + n;
  int e = 31 - __clz(n);
  unsigned nn = (unsigned)n * (unsigned)n;
  int f = 2 * e + ((nn >= (1u << (2 * e + 1))) ? 1 : 0) - 6;
  int val = 8 + f;
  if (val > 15) val = 15;
  return ret + val;
}

// ---------- fused prep ----------
__global__ __launch_bounds__(256) void prep(
    const float* __restrict__ wq, const float* __restrict__ wk,
    const float* __restrict__ wv, const float* __restrict__ fcw,
    const float* __restrict__ wi, const float* __restrict__ wo,
    const float* __restrict__ bq, const float* __restrict__ bk,
    const float* __restrict__ bv, const float* __restrict__ rel_bias,
    u16* __restrict__ wqb, u16* __restrict__ wkb, u16* __restrict__ wvb,
    u16* __restrict__ fcwb, u16* __restrict__ wib, u16* __restrict__ wob,
    float* __restrict__ fb, float* __restrict__ tab) {
  const int blk = blockIdx.x, t = threadIdx.x;
  if (blk < 12288) {
    const float* s; u16* d; int rel;
    if (blk < 1024)      { s = wq;  d = wqb;  rel = blk; }
    else if (blk < 2048) { s = wk;  d = wkb;  rel = blk - 1024; }
    else if (blk < 3072) { s = wv;  d = wvb;  rel = blk - 2048; }
    else if (blk < 4096) { s = fcw; d = fcwb; rel = blk - 3072; }
    else if (blk < 8192) { s = wi;  d = wib;  rel = blk - 4096; }
    else                 { s = wo;  d = wob;  rel = blk - 8192; }
    const int i = (rel * 256 + t) * 4;
    float4 v = *(const float4*)&s[i];
    d[i + 0] = f2bf(v.x); d[i + 1] = f2bf(v.y);
    d[i + 2] = f2bf(v.z); d[i + 3] = f2bf(v.w);
  } else if (blk < 12300) {
    const int i = (blk - 12288) * 256 + t;   // 3072
    fb[i] = i < 1024 ? bq[i] : (i < 2048 ? bk[i - 1024] : bv[i - 2048]);
  } else {
    const int idx = (blk - 12300) * 256 + t; // 16*2048
    const int h = idx >> 11;
    const int rel = (idx & 2047) - 1024;
    tab[idx] = rel_bias[bucket_fn(rel) * 16 + h];
  }
}

__global__ __launch_bounds__(256) void write_pb(const float* __restrict__ tab,
                                                float* __restrict__ pb) {
  const int i = blockIdx.x, h = blockIdx.y, t = threadIdx.x;
  __shared__ float tabs[2048];
  ((float4*)tabs)[t]       = ((const float4*)(tab + h * 2048))[t];
  ((float4*)tabs)[t + 256] = ((const float4*)(tab + h * 2048))[t + 256];
  __syncthreads();
  const int j = t * 4;
  float4 o;
  o.x = tabs[j + 0 - i + 1024];
  o.y = tabs[j + 1 - i + 1024];
  o.z = tabs[j + 2 - i + 1024];
  o.w = tabs[j + 3 - i + 1024];
#pragma unroll
  for (int b = 0; b < 4; b++)
    *(float4*)&pb[(((size_t)(b * 16 + h)) * 1024 + i) * 1024 + j] = o;
}

__global__ __launch_bounds__(256) void t5_ln(const float* __restrict__ x,
                                             const float* __restrict__ wgt,
                                             float eps, u16* __restrict__ out) {
  const int row = blockIdx.x, t = threadIdx.x;
  const float4 v = ((const float4*)(x + (size_t)row * 1024))[t];
  float ss = v.x * v.x + v.y * v.y + v.z * v.z + v.w * v.w;
#pragma unroll
  for (int off = 1; off < 64; off <<= 1) ss += __shfl_xor(ss, off, 64);
  __shared__ float red[4];
  if ((t & 63) == 0) red[t >> 6] = ss;
  __syncthreads();
  float tot = red[0] + red[1] + red[2] + red[3];
  float inv = 1.0f / sqrtf(tot * (1.0f / 1024.0f) + eps);
  const float4 wv = ((const float4*)wgt)[t];
  u16* o = out + (size_t)row * 1024 + t * 4;
  o[0] = f2bf(v.x * inv * wv.x);
  o[1] = f2bf(v.y * inv * wv.y);
  o[2] = f2bf(v.z * inv * wv.z);
  o[3] = f2bf(v.w * inv * wv.w);
}

__global__ __launch_bounds__(256) void transpose_v(const u16* __restrict__ v,
                                                   u16* __restrict__ vt) {
  __shared__ u16 T[64][72];
  const int bh = blockIdx.y;
  const int l0 = blockIdx.x * 64;
  const int t = threadIdx.x;
  const int sr = t >> 3, sc = (t & 7) * 8;
  const u16* vb = v + (size_t)bh * 65536;
  *(short8*)&T[sr][sc]      = *(const short8*)&vb[(size_t)(l0 + sr) * 64 + sc];
  *(short8*)&T[sr + 32][sc] = *(const short8*)&vb[(size_t)(l0 + sr + 32) * 64 + sc];
  __syncthreads();
  u16* vtb = vt + (size_t)bh * 65536;
  short8 o0, o1;
#pragma unroll
  for (int u = 0; u < 8; u++) {
    ((u16*)&o0)[u] = T[sc + u][sr];
    ((u16*)&o1)[u] = T[sc + u][sr + 32];
  }
  *(short8*)&vtb[(size_t)sr * 1024 + l0 + sc]        = o0;
  *(short8*)&vtb[(size_t)(sr + 32) * 1024 + l0 + sc] = o1;
}

// ---------- GEMM 128x128: bf16 out via LDS epilogue + XCD swizzle ----------
// Stage issued right after barrier (before ds_reads): loads go out earlier,
// same race-safety (barrier guards buffer reuse, vmcnt order-preserved).
// MODE 0: (acc+fb[col])*sel_scale -> bf16 permuted [b,h,pos,dk], QKV fused (N=3072)
// MODE 2: gelu(acc) -> bf16 row-major
template<int MODE>
__global__ __launch_bounds__(256, 3) void gemm_nt(
    const u16* __restrict__ A, const u16* __restrict__ Bw,
    int M, int N, int K,
    const float* __restrict__ bias, const float* __restrict__ res,
    float scale, float* __restrict__ outF, u16* __restrict__ outB) {
  __shared__ u16 As[3][4096];
  __shared__ u16 Bs[3][4096];
  const int t = threadIdx.x;
  const int w = t >> 6, lane = t & 63;
  const int wr = w >> 1, wc = w & 1;
  const int g = lane >> 4, lc = lane & 15;

  const int nwg = gridDim.x * gridDim.y;
  const int flat = xcd_swz(blockIdx.y * gridDim.x + blockIdx.x, nwg);
  const int bx = flat % gridDim.x, by = flat / gridDim.x;
  const int m0 = by * 128, n0 = bx * 128;

  const int srow = w * 16 + (lane >> 2);
  const int sc8  = (lane & 3) ^ ((srow >> 1) & 3);
  const u16* Ag = &A[(size_t)(m0 + srow) * K + sc8 * 8];
  const u16* Bg = &Bw[(size_t)(n0 + srow) * K + sc8 * 8];
  const size_t row64 = (size_t)64 * K;
  const int swz = (lc >> 1) & 3;

  const int NT = K >> 5;
  f32x4 acc[4][4] = {};

  auto stage = [&](int buf, int tt) {
    const int k0 = tt << 5;
    u16* lA = &As[buf][w * 512];
    u16* lB = &Bs[buf][w * 512];
    gload16(Ag + k0, lA);
    gload16(Ag + row64 + k0, lA + 2048);
    gload16(Bg + k0, lB);
    gload16(Bg + row64 + k0, lB + 2048);
  };

  stage(0, 0);
  stage(1, 1);

  for (int tt = 0; tt < NT; tt++) {
    const int cur = tt % 3;
    if (tt < NT - 1) {
      asm volatile("s_waitcnt vmcnt(4)" ::: "memory");
    } else {
      asm volatile("s_waitcnt vmcnt(0)" ::: "memory");
    }
    __builtin_amdgcn_s_barrier();
    if (tt + 2 < NT) stage((tt + 2) % 3, tt + 2);   // issue loads early
    short8 af[4], bf[4];
#pragma unroll
    for (int mi = 0; mi < 4; mi++)
      af[mi] = *(short8*)&As[cur][(wr * 64 + mi * 16 + lc) * 32 + (g ^ swz) * 8];
#pragma unroll
    for (int ni = 0; ni < 4; ni++)
      bf[ni] = *(short8*)&Bs[cur][(wc * 64 + ni * 16 + lc) * 32 + (g ^ swz) * 8];
#pragma unroll
    for (int mi = 0; mi < 4; mi++)
#pragma unroll
      for (int ni = 0; ni < 4; ni++)
        acc[mi][ni] = __builtin_amdgcn_mfma_f32_16x16x32_bf16(af[mi], bf[ni], acc[mi][ni], 0, 0, 0);
  }

  // ---- epilogue: per-mi re-layout through LDS -> coalesced 16B stores ----
  u16* Es = &As[0][0];
  __syncthreads();
#pragma unroll
  for (int mi = 0; mi < 4; mi++) {
#pragma unroll
    for (int ni = 0; ni < 4; ni++) {
#pragma unroll
      for (int r = 0; r < 4; r++) {
        const int col = n0 + wc * 64 + ni * 16 + lc;
        float v = acc[mi][ni][r];
        if (MODE == 0) {
          v = (v + bias[col]) * ((col >> 10) == 0 ? scale : 1.0f);
        } else {
          v = 0.5f * v * (1.0f + erff(v * 0.70710678118654752440f));
        }
        Es[wr * 2048 + (g * 4 + r) * 128 + wc * 64 + ni * 16 + lc] = f2bf(v);
      }
    }
    __syncthreads();
    {
      const int rr = t >> 3;
      const int wr2 = rr >> 4, r16 = rr & 15;
      const int cc = (t & 7) * 16;
      short8 o0 = *(short8*)&Es[wr2 * 2048 + r16 * 128 + cc];
      short8 o1 = *(short8*)&Es[wr2 * 2048 + r16 * 128 + cc + 8];
      const int row = m0 + wr2 * 64 + mi * 16 + r16;
      if (MODE == 0) {
        const int col0 = n0 + cc;
        const int which = col0 >> 10, c = col0 & 1023;
        const int hh = c >> 6, dk = c & 63;
        const int b = row >> 10, pos = row & 1023;
        u16* dst = outB + (size_t)which * 4194304 +
                   (((size_t)(b * 16 + hh)) * 1024 + pos) * 64 + dk;
        *(short8*)dst = o0;
        *(short8*)(dst + 8) = o1;
      } else {
        u16* dst = outB + (size_t)row * (size_t)N + n0 + cc;
        *(short8*)dst = o0;
        *(short8*)(dst + 8) = o1;
      }
    }
    __syncthreads();
  }
}

// ---------- GEMM 64x128 tile (FC / FFN2: 512 blocks = 2/CU) + XCD swizzle ----------
template<int MODE>
__global__ __launch_bounds__(256, 4) void gemm_nt64(
    const u16* __restrict__ A, const u16* __restrict__ Bw,
    int M, int N, int K,
    const float* __restrict__ bias, const float* __restrict__ res,
    float* __restrict__ outF) {
  __shared__ u16 As[3][2048];
  __shared__ u16 Bs[3][4096];
  const int t = threadIdx.x;
  const int w = t >> 6, lane = t & 63;
  const int wr = w >> 1, wc = w & 1;
  const int g = lane >> 4, lc = lane & 15;

  const int nwg = gridDim.x * gridDim.y;
  const int flat = xcd_swz(blockIdx.y * gridDim.x + blockIdx.x, nwg);
  const int bx = flat % gridDim.x, by = flat / gridDim.x;
  const int m0 = by * 64, n0 = bx * 128;

  const int srow = w * 16 + (lane >> 2);
  const int sc8  = (lane & 3) ^ ((srow >> 1) & 3);
  const u16* Ag = &A[(size_t)(m0 + srow) * K + sc8 * 8];
  const u16* Bg = &Bw[(size_t)(n0 + srow) * K + sc8 * 8];
  const size_t row64 = (size_t)64 * K;
  const int swz = (lc >> 1) & 3;

  const int NT = K >> 5;
  f32x4 acc[2][4] = {};

  auto stage = [&](int buf, int tt) {
    const int k0 = tt << 5;
    gload16(Ag + k0, &As[buf][w * 512]);
    gload16(Bg + k0, &Bs[buf][w * 512]);
    gload16(Bg + row64 + k0, &Bs[buf][w * 512 + 2048]);
  };

  stage(0, 0);
  stage(1, 1);

  for (int tt = 0; tt < NT; tt++) {
    const int cur = tt % 3;
    if (tt < NT - 1) {
      asm volatile("s_waitcnt vmcnt(3)" ::: "memory");
    } else {
      asm volatile("s_waitcnt vmcnt(0)" ::: "memory");
    }
    __builtin_amdgcn_s_barrier();
    if (tt + 2 < NT) stage((tt + 2) % 3, tt + 2);   // issue loads early
    short8 af[2], bf[4];
#pragma unroll
    for (int mi = 0; mi < 2; mi++)
      af[mi] = *(short8*)&As[cur][(wr * 32 + mi * 16 + lc) * 32 + (g ^ swz) * 8];
#pragma unroll
    for (int ni = 0; ni < 4; ni++)
      bf[ni] = *(short8*)&Bs[cur][(wc * 64 + ni * 16 + lc) * 32 + (g ^ swz) * 8];
#pragma unroll
    for (int mi = 0; mi < 2; mi++)
#pragma unroll
      for (int ni = 0; ni < 4; ni++)
        acc[mi][ni] = __builtin_amdgcn_mfma_f32_16x16x32_bf16(af[mi], bf[ni], acc[mi][ni], 0, 0, 0);
  }

#pragma unroll
  for (int mi = 0; mi < 2; mi++) {
#pragma unroll
    for (int ni = 0; ni < 4; ni++) {
#pragma unroll
      for (int r = 0; r < 4; r++) {
        const int row = m0 + wr * 32 + mi * 16 + g * 4 + r;
        const int col = n0 + wc * 64 + ni * 16 + lc;
        float v = acc[mi][ni][r];
        if (MODE == 1) {
          v += bias[col] + res[(size_t)row * 1024 + col];
        } else {
          v += res[(size_t)row * 1024 + col];
        }
        outF[(size_t)row * 1024 + col] = v;
      }
    }
  }
}

// ---------- flash attention: ctx + (m,l), exp2 domain, XCD swizzle ----------
__global__ __launch_bounds__(256) void attn_kernel(
    const u16* __restrict__ q, const u16* __restrict__ k,
    const u16* __restrict__ vt, const float* __restrict__ tab,
    u16* __restrict__ ctx, float* __restrict__ ml) {
  const int flat = xcd_swz(blockIdx.y * 16 + blockIdx.x, 1024);
  const int bh = flat / 16;
  const int i0 = (flat % 16) * 64;
  const int h = bh & 15, b = bh >> 4;
  const int t = threadIdx.x, w = t >> 6, lane = t & 63;
  const int g = lane >> 4, lc = lane & 15;
  const int sr = t >> 3;
  const int swc = ((t & 7) ^ (sr & 7)) * 8;
  const int sc = (t & 7) * 8;

  __shared__ u16 Ks[2][64][64];
  __shared__ u16 Vts[2][64][64];
  __shared__ u16 P[4][16][64];
  __shared__ float tabs[2048];

  const u16* qb  = q + (size_t)bh * 65536;
  const u16* kb  = k + (size_t)bh * 65536;
  const u16* vtb = vt + (size_t)bh * 65536;

  {
    float4 t0 = ((const float4*)(tab + h * 2048))[t];
    float4 t1 = ((const float4*)(tab + h * 2048))[t + 256];
    t0.x *= L2E; t0.y *= L2E; t0.z *= L2E; t0.w *= L2E;
    t1.x *= L2E; t1.y *= L2E; t1.z *= L2E; t1.w *= L2E;
    ((float4*)tabs)[t]       = t0;
    ((float4*)tabs)[t + 256] = t1;
  }

  const short8 aq0 = *(const short8*)&qb[(size_t)(i0 + w * 16 + lc) * 64 + g * 8];
  const short8 aq1 = *(const short8*)&qb[(size_t)(i0 + w * 16 + lc) * 64 + 32 + g * 8];

  {
    short8 ka = *(const short8*)&kb[(size_t)sr * 64 + sc];
    short8 kc = *(const short8*)&kb[(size_t)(sr + 32) * 64 + sc];
    short8 va = *(const short8*)&vtb[(size_t)sr * 1024 + sc];
    short8 vc = *(const short8*)&vtb[(size_t)(sr + 32) * 1024 + sc];
    *(short8*)&Ks[0][sr][swc]       = ka;
    *(short8*)&Ks[0][sr + 32][swc]  = kc;
    *(short8*)&Vts[0][sr][swc]      = va;
    *(short8*)&Vts[0][sr + 32][swc] = vc;
  }
  __syncthreads();

  const int rx = lc & 7;
  const int ibase = 1024 - i0 - (w * 16 + g * 4) + lc;

  float m_r[4] = {-INFINITY, -INFINITY, -INFINITY, -INFINITY};
  float l_r[4] = {0.f, 0.f, 0.f, 0.f};
  f32x4 cacc[4] = {};

  for (int tt = 0; tt < 16; tt++) {
    const int buf = tt & 1;
    const int j0 = tt * 64;

    short8 nka, nkc, nva, nvc;
    if (tt < 15) {
      const int jn = j0 + 64;
      nka = *(const short8*)&kb[(size_t)(jn + sr) * 64 + sc];
      nkc = *(const short8*)&kb[(size_t)(jn + sr + 32) * 64 + sc];
      nva = *(const short8*)&vtb[(size_t)sr * 1024 + jn + sc];
      nvc = *(const short8*)&vtb[(size_t)(sr + 32) * 1024 + jn + sc];
    }

    f32x4 s[4] = {};
#pragma unroll
    for (int ni = 0; ni < 4; ni++) {
      short8 b0 = *(short8*)&Ks[buf][ni * 16 + lc][(g ^ rx) * 8];
      short8 b1 = *(short8*)&Ks[buf][ni * 16 + lc][((4 + g) ^ rx) * 8];
      s[ni] = __builtin_amdgcn_mfma_f32_16x16x32_bf16(aq0, b0, s[ni], 0, 0, 0);
      s[ni] = __builtin_amdgcn_mfma_f32_16x16x32_bf16(aq1, b1, s[ni], 0, 0, 0);
    }
#pragma unroll
    for (int ni = 0; ni < 4; ni++)
#pragma unroll
      for (int r = 0; r < 4; r++)
        s[ni][r] += tabs[ibase + j0 + ni * 16 - r];

#pragma unroll
    for (int r = 0; r < 4; r++) {
      float tm = fmaxf(fmaxf(s[0][r], s[1][r]), fmaxf(s[2][r], s[3][r]));
#pragma unroll
      for (int off = 1; off < 16; off <<= 1) tm = fmaxf(tm, __shfl_xor(tm, off, 64));
      const float mn = fmaxf(m_r[r], tm);
      const float scl = __builtin_amdgcn_exp2f(m_r[r] - mn);
      float rs = 0.f;
#pragma unroll
      for (int ni = 0; ni < 4; ni++) {
        float p = __builtin_amdgcn_exp2f(s[ni][r] - mn);
        s[ni][r] = p;
        rs += p;
      }
#pragma unroll
      for (int off = 1; off < 16; off <<= 1) rs += __shfl_xor(rs, off, 64);
      l_r[r] = l_r[r] * scl + rs;
      m_r[r] = mn;
#pragma unroll
      for (int d = 0; d < 4; d++) cacc[d][r] *= scl;
    }

#pragma unroll
    for (int ni = 0; ni < 4; ni++)
#pragma unroll
      for (int r = 0; r < 4; r++) {
        const int prow = g * 4 + r;
        P[w][prow][(((ni * 2 + (lc >> 3)) ^ (prow & 7)) << 3) | (lc & 7)] = f2bf(s[ni][r]);
      }

    short8 ap0 = *(short8*)&P[w][lc][(g ^ rx) * 8];
    short8 ap1 = *(short8*)&P[w][lc][((4 + g) ^ rx) * 8];
#pragma unroll
    for (int d = 0; d < 4; d++) {
      short8 bv0 = *(short8*)&Vts[buf][d * 16 + lc][(g ^ rx) * 8];
      short8 bv1 = *(short8*)&Vts[buf][d * 16 + lc][((4 + g) ^ rx) * 8];
      cacc[d] = __builtin_amdgcn_mfma_f32_16x16x32_bf16(ap0, bv0, cacc[d], 0, 0, 0);
      cacc[d] = __builtin_amdgcn_mfma_f32_16x16x32_bf16(ap1, bv1, cacc[d], 0, 0, 0);
    }

    if (tt < 15) {
      *(short8*)&Ks[buf ^ 1][sr][swc]       = nka;
      *(short8*)&Ks[buf ^ 1][sr + 32][swc]  = nkc;
      *(short8*)&Vts[buf ^ 1][sr][swc]      = nva;
      *(short8*)&Vts[buf ^ 1][sr + 32][swc] = nvc;
    }
    __syncthreads();
  }

  float inv[4];
#pragma unroll
  for (int r = 0; r < 4; r++) inv[r] = 1.0f / l_r[r];
#pragma unroll
  for (int d = 0; d < 4; d++)
#pragma unroll
    for (int r = 0; r < 4; r++) {
      const int pos = i0 + w * 16 + g * 4 + r;
      ctx[((size_t)b * 1024 + pos) * 1024 + h * 64 + d * 16 + lc] = f2bf(cacc[d][r] * inv[r]);
    }
  if (lc == 0) {
#pragma unroll
    for (int r = 0; r < 4; r++) {
      const int i = i0 + w * 16 + g * 4 + r;
      ml[(size_t)bh * 1024 + i] = m_r[r];
      ml[65536 + (size_t)bh * 1024 + i] = l_r[r];
    }
  }
}

// ---------- attn_sum: recompute scores (exp2 domain), sum over heads ----------
__global__ __launch_bounds__(256) void attn_sum_kernel(
    const u16* __restrict__ q, const u16* __restrict__ k,
    const float* __restrict__ tab, const float* __restrict__ ml,
    float* __restrict__ asum) {
  const int flat = xcd_swz(((blockIdx.z * 16 + blockIdx.y) * 16) + blockIdx.x, 1024);
  const int j0 = (flat % 16) * 64;
  const int i0 = ((flat / 16) % 16) * 64;
  const int b = flat / 256;
  const int t = threadIdx.x, w = t >> 6, lane = t & 63;
  const int g = lane >> 4, lc = lane & 15;
  const int sr = t >> 3;
  const int swc = ((t & 7) ^ (sr & 7)) * 8;
  const int sc = (t & 7) * 8;
  const int rx = lc & 7;
  __shared__ u16 Ks[64][64];
  __shared__ float tabs[128];

  f32x4 acc[4] = {};

  for (int h = 0; h < 16; h++) {
    const int bh = b * 16 + h;
    __syncthreads();
    const u16* kb = k + (size_t)bh * 65536;
    *(short8*)&Ks[sr][swc]      = *(const short8*)&kb[(size_t)(j0 + sr) * 64 + sc];
    *(short8*)&Ks[sr + 32][swc] = *(const short8*)&kb[(size_t)(j0 + sr + 32) * 64 + sc];
    if (t < 127) tabs[t] = tab[h * 2048 + (j0 - i0 - 63 + t) + 1024] * L2E;
    __syncthreads();
    const u16* qb = q + (size_t)bh * 65536;
    short8 aq0 = *(const short8*)&qb[(size_t)(i0 + w * 16 + lc) * 64 + g * 8];
    short8 aq1 = *(const short8*)&qb[(size_t)(i0 + w * 16 + lc) * 64 + 32 + g * 8];
    f32x4 s[4] = {};
#pragma unroll
    for (int ni = 0; ni < 4; ni++) {
      short8 b0 = *(short8*)&Ks[ni * 16 + lc][(g ^ rx) * 8];
      short8 b1 = *(short8*)&Ks[ni * 16 + lc][((4 + g) ^ rx) * 8];
      s[ni] = __builtin_amdgcn_mfma_f32_16x16x32_bf16(aq0, b0, s[ni], 0, 0, 0);
      s[ni] = __builtin_amdgcn_mfma_f32_16x16x32_bf16(aq1, b1, s[ni], 0, 0, 0);
    }
    float mm[4], li[4];
#pragma unroll
    for (int r = 0; r < 4; r++) {
      const int i = i0 + w * 16 + g * 4 + r;
      mm[r] = ml[(size_t)bh * 1024 + i];
      li[r] = 1.0f / ml[65536 + (size_t)bh * 1024 + i];
    }
#pragma unroll
    for (int ni = 0; ni < 4; ni++)
#pragma unroll
      for (int r = 0; r < 4; r++) {
        float sv = s[ni][r] + tabs[ni * 16 + lc - w * 16 - g * 4 - r + 63];
        acc[ni][r] += __builtin_amdgcn_exp2f(sv - mm[r]) * li[r];
      }
  }
#pragma unroll
  for (int ni = 0; ni < 4; ni++)
#pragma unroll
    for (int r = 0; r < 4; r++) {
      const int i = i0 + w * 16 + g * 4 + r;
      asum[((size_t)b * 1024 + i) * 1024 + j0 + ni * 16 + lc] = acc[ni][r];
    }
}

// ---------- launch ----------
extern "C" void kernel_launch(void* const* d_in, const int* in_sizes, int n_in,
                              void* d_out, int out_size, void* d_ws, size_t ws_size,
                              hipStream_t stream) {
  const float* src      = (const float*)d_in[0];
  const float* ln1_w    = (const float*)d_in[2];
  const float* wq       = (const float*)d_in[3];
  const float* bq       = (const float*)d_in[4];
  const float* wk       = (const float*)d_in[5];
  const float* bk       = (const float*)d_in[6];
  const float* wv       = (const float*)d_in[7];
  const float* bv       = (const float*)d_in[8];
  const float* fc_w     = (const float*)d_in[9];
  const float* fc_b     = (const float*)d_in[10];
  const float* rel_bias = (const float*)d_in[11];
  const float* ln2_w    = (const float*)d_in[12];
  const float* wi       = (const float*)d_in[13];
  const float* wo       = (const float*)d_in[14];

  const size_t MB = 1u << 20;
  char* ws = (char*)d_ws;
  u16* wq_b   = (u16*)(ws + 0 * MB);     // wq/wk/wv contiguous = fused [3072][1024]
  u16* wk_b   = (u16*)(ws + 2 * MB);
  u16* wv_b   = (u16*)(ws + 4 * MB);
  u16* fcw_b  = (u16*)(ws + 6 * MB);
  u16* wi_b   = (u16*)(ws + 8 * MB);
  u16* wo_b   = (u16*)(ws + 16 * MB);
  u16* proj_b = (u16*)(ws + 24 * MB);   // reused as nx
  u16* q_b    = (u16*)(ws + 32 * MB);   // q/k/v contiguous, 4M u16 apart
  u16* k_b    = (u16*)(ws + 40 * MB);
  u16* v_b    = (u16*)(ws + 48 * MB);
  u16* vt_b   = (u16*)(ws + 56 * MB);
  u16* h_b    = (u16*)(ws + 32 * MB);   // aliases q/k/v/vt (dead by then)
  u16* ctx_b  = (u16*)(ws + 64 * MB);
  float* attn_out = (float*)(ws + 72 * MB);
  float* ml   = (float*)(ws + 88 * MB);
  float* tab  = (float*)(ws + 88 * MB + 512 * 1024);
  float* fb   = (float*)(ws + 90 * MB);

  float* outF = (float*)d_out;
  float* asum = outF + 4194304;
  float* pb   = outF + 8388608;

  prep<<<12428, 256, 0, stream>>>(wq, wk, wv, fc_w, wi, wo, bq, bk, bv, rel_bias,
                                  wq_b, wk_b, wv_b, fcw_b, wi_b, wo_b, fb, tab);

  write_pb<<<dim3(1024, 16), 256, 0, stream>>>(tab, pb);

  t5_ln<<<4096, 256, 0, stream>>>(src, ln1_w, 1e-12f, proj_b);

  // fused QKV: 128x128 tiles, 768 blocks = exactly 3 rounds at 3/CU
  gemm_nt<0><<<dim3(24, 32), 256, 0, stream>>>(proj_b, wq_b, 4096, 3072, 1024, fb, nullptr,
                                               0.125f * L2E, nullptr, q_b);

  transpose_v<<<dim3(16, 64), 256, 0, stream>>>(v_b, vt_b);
  attn_kernel<<<dim3(16, 64), 256, 0, stream>>>(q_b, k_b, vt_b, tab, ctx_b, ml);
  attn_sum_kernel<<<dim3(16, 16, 4), 256, 0, stream>>>(q_b, k_b, tab, ml, asum);

  // FC: 64x128 tile -> 512 blocks = 2/CU
  gemm_nt64<1><<<dim3(8, 64), 256, 0, stream>>>(ctx_b, fcw_b, 4096, 1024, 1024, fc_b, src, attn_out);

  t5_ln<<<4096, 256, 0, stream>>>(attn_out, ln2_w, 1e-6f, proj_b);

  // FFN1: 128x128 tiles (R10-proven config)
  gemm_nt<2><<<dim3(32, 32), 256, 0, stream>>>(proj_b, wi_b, 4096, 4096, 1024, nullptr, nullptr,
                                               1.0f, nullptr, h_b);
  // FFN2: 64x128 tile -> 512 blocks = 2/CU
  gemm_nt64<3><<<dim3(8, 64), 256, 0, stream>>>(h_b, wo_b, 4096, 1024, 4096, nullptr, attn_out, outF);
}

// Round 13
// 329.778 us; speedup vs baseline: 1.0929x; 1.0668x over previous
//
#include <hip/hip_runtime.h>
#include <hip/hip_bf16.h>
#include <math.h>

typedef __attribute__((ext_vector_type(8))) short short8;
typedef __attribute__((ext_vector_type(4))) float f32x4;
typedef unsigned short u16;

#define L2E 1.44269504088896340736f

// ---------- helpers ----------
__device__ __forceinline__ u16 f2bf(float f) {
  union { float f; unsigned u; } x; x.f = f;
  unsigned r = x.u + 0x7fffu + ((x.u >> 16) & 1u);   // RNE
  return (u16)(r >> 16);
}

__device__ __forceinline__ void gload16(const void* g, void* l) {
  auto gp = reinterpret_cast<const __attribute__((address_space(1))) void*>(
      reinterpret_cast<uintptr_t>(g));
  auto lp = reinterpret_cast<__attribute__((address_space(3))) void*>(
      reinterpret_cast<uintptr_t>(l));
  __builtin_amdgcn_global_load_lds(gp, lp, 16, 0, 0);
}

// XCD-aware chunked remap (T1). Requires nwg % 8 == 0 (bijective).
__device__ __forceinline__ int xcd_swz(int flat, int nwg) {
  return (flat & 7) * (nwg >> 3) + (flat >> 3);
}

// exact T5 bucket: matches floor(2*log2(n/8)) with integer arithmetic
__device__ __forceinline__ int bucket_fn(int rel) {
  int n = -rel;              // i - j
  int ret = 0;
  if (n < 0) { ret = 16; n = -n; }
  if (n < 8) return ret + n;
  int e = 31 - __clz(n);
  unsigned nn = (unsigned)n * (unsigned)n;
  int f = 2 * e + ((nn >= (1u << (2 * e + 1))) ? 1 : 0) - 6;
  int val = 8 + f;
  if (val > 15) val = 15;
  return ret + val;
}

// ---------- fused prep ----------
__global__ __launch_bounds__(256) void prep(
    const float* __restrict__ wq, const float* __restrict__ wk,
    const float* __restrict__ wv, const float* __restrict__ fcw,
    const float* __restrict__ wi, const float* __restrict__ wo,
    const float* __restrict__ bq, const float* __restrict__ bk,
    const float* __restrict__ bv, const float* __restrict__ rel_bias,
    u16* __restrict__ wqb, u16* __restrict__ wkb, u16* __restrict__ wvb,
    u16* __restrict__ fcwb, u16* __restrict__ wib, u16* __restrict__ wob,
    float* __restrict__ fb, float* __restrict__ tab) {
  const int blk = blockIdx.x, t = threadIdx.x;
  if (blk < 12288) {
    const float* s; u16* d; int rel;
    if (blk < 1024)      { s = wq;  d = wqb;  rel = blk; }
    else if (blk < 2048) { s = wk;  d = wkb;  rel = blk - 1024; }
    else if (blk < 3072) { s = wv;  d = wvb;  rel = blk - 2048; }
    else if (blk < 4096) { s = fcw; d = fcwb; rel = blk - 3072; }
    else if (blk < 8192) { s = wi;  d = wib;  rel = blk - 4096; }
    else                 { s = wo;  d = wob;  rel = blk - 8192; }
    const int i = (rel * 256 + t) * 4;
    float4 v = *(const float4*)&s[i];
    d[i + 0] = f2bf(v.x); d[i + 1] = f2bf(v.y);
    d[i + 2] = f2bf(v.z); d[i + 3] = f2bf(v.w);
  } else if (blk < 12300) {
    const int i = (blk - 12288) * 256 + t;   // 3072
    fb[i] = i < 1024 ? bq[i] : (i < 2048 ? bk[i - 1024] : bv[i - 2048]);
  } else {
    const int idx = (blk - 12300) * 256 + t; // 16*2048
    const int h = idx >> 11;
    const int rel = (idx & 2047) - 1024;
    tab[idx] = rel_bias[bucket_fn(rel) * 16 + h];
  }
}

__global__ __launch_bounds__(256) void t5_ln(const float* __restrict__ x,
                                             const float* __restrict__ wgt,
                                             float eps, u16* __restrict__ out) {
  const int row = blockIdx.x, t = threadIdx.x;
  const float4 v = ((const float4*)(x + (size_t)row * 1024))[t];
  float ss = v.x * v.x + v.y * v.y + v.z * v.z + v.w * v.w;
#pragma unroll
  for (int off = 1; off < 64; off <<= 1) ss += __shfl_xor(ss, off, 64);
  __shared__ float red[4];
  if ((t & 63) == 0) red[t >> 6] = ss;
  __syncthreads();
  float tot = red[0] + red[1] + red[2] + red[3];
  float inv = 1.0f / sqrtf(tot * (1.0f / 1024.0f) + eps);
  const float4 wv = ((const float4*)wgt)[t];
  u16* o = out + (size_t)row * 1024 + t * 4;
  o[0] = f2bf(v.x * inv * wv.x);
  o[1] = f2bf(v.y * inv * wv.y);
  o[2] = f2bf(v.z * inv * wv.z);
  o[3] = f2bf(v.w * inv * wv.w);
}

__global__ __launch_bounds__(256) void transpose_v(const u16* __restrict__ v,
                                                   u16* __restrict__ vt) {
  __shared__ u16 T[64][72];
  const int bh = blockIdx.y;
  const int l0 = blockIdx.x * 64;
  const int t = threadIdx.x;
  const int sr = t >> 3, sc = (t & 7) * 8;
  const u16* vb = v + (size_t)bh * 65536;
  *(short8*)&T[sr][sc]      = *(const short8*)&vb[(size_t)(l0 + sr) * 64 + sc];
  *(short8*)&T[sr + 32][sc] = *(const short8*)&vb[(size_t)(l0 + sr + 32) * 64 + sc];
  __syncthreads();
  u16* vtb = vt + (size_t)bh * 65536;
  short8 o0, o1;
#pragma unroll
  for (int u = 0; u < 8; u++) {
    ((u16*)&o0)[u] = T[sc + u][sr];
    ((u16*)&o1)[u] = T[sc + u][sr + 32];
  }
  *(short8*)&vtb[(size_t)sr * 1024 + l0 + sc]        = o0;
  *(short8*)&vtb[(size_t)(sr + 32) * 1024 + l0 + sc] = o1;
}

// ---------- GEMM 128x128: bf16 out via LDS epilogue + XCD swizzle ----------
// MODE 0: (acc+fb[col])*sel_scale -> bf16 permuted [b,h,pos,dk], QKV fused (N=3072)
// MODE 2: gelu(acc) -> bf16 row-major
template<int MODE>
__global__ __launch_bounds__(256, 3) void gemm_nt(
    const u16* __restrict__ A, const u16* __restrict__ Bw,
    int M, int N, int K,
    const float* __restrict__ bias, const float* __restrict__ res,
    float scale, float* __restrict__ outF, u16* __restrict__ outB) {
  __shared__ u16 As[3][4096];
  __shared__ u16 Bs[3][4096];
  const int t = threadIdx.x;
  const int w = t >> 6, lane = t & 63;
  const int wr = w >> 1, wc = w & 1;
  const int g = lane >> 4, lc = lane & 15;

  const int nwg = gridDim.x * gridDim.y;
  const int flat = xcd_swz(blockIdx.y * gridDim.x + blockIdx.x, nwg);
  const int bx = flat % gridDim.x, by = flat / gridDim.x;
  const int m0 = by * 128, n0 = bx * 128;

  const int srow = w * 16 + (lane >> 2);
  const int sc8  = (lane & 3) ^ ((srow >> 1) & 3);
  const u16* Ag = &A[(size_t)(m0 + srow) * K + sc8 * 8];
  const u16* Bg = &Bw[(size_t)(n0 + srow) * K + sc8 * 8];
  const size_t row64 = (size_t)64 * K;
  const int swz = (lc >> 1) & 3;

  const int NT = K >> 5;
  f32x4 acc[4][4] = {};

  auto stage = [&](int buf, int tt) {
    const int k0 = tt << 5;
    u16* lA = &As[buf][w * 512];
    u16* lB = &Bs[buf][w * 512];
    gload16(Ag + k0, lA);
    gload16(Ag + row64 + k0, lA + 2048);
    gload16(Bg + k0, lB);
    gload16(Bg + row64 + k0, lB + 2048);
  };

  stage(0, 0);
  stage(1, 1);

  for (int tt = 0; tt < NT; tt++) {
    const int cur = tt % 3;
    if (tt < NT - 1) {
      asm volatile("s_waitcnt vmcnt(4)" ::: "memory");
    } else {
      asm volatile("s_waitcnt vmcnt(0)" ::: "memory");
    }
    __builtin_amdgcn_s_barrier();
    if (tt + 2 < NT) stage((tt + 2) % 3, tt + 2);   // issue loads early
    short8 af[4], bf[4];
#pragma unroll
    for (int mi = 0; mi < 4; mi++)
      af[mi] = *(short8*)&As[cur][(wr * 64 + mi * 16 + lc) * 32 + (g ^ swz) * 8];
#pragma unroll
    for (int ni = 0; ni < 4; ni++)
      bf[ni] = *(short8*)&Bs[cur][(wc * 64 + ni * 16 + lc) * 32 + (g ^ swz) * 8];
#pragma unroll
    for (int mi = 0; mi < 4; mi++)
#pragma unroll
      for (int ni = 0; ni < 4; ni++)
        acc[mi][ni] = __builtin_amdgcn_mfma_f32_16x16x32_bf16(af[mi], bf[ni], acc[mi][ni], 0, 0, 0);
  }

  // ---- epilogue: per-mi re-layout through LDS -> coalesced 16B stores ----
  u16* Es = &As[0][0];
  __syncthreads();
#pragma unroll
  for (int mi = 0; mi < 4; mi++) {
#pragma unroll
    for (int ni = 0; ni < 4; ni++) {
#pragma unroll
      for (int r = 0; r < 4; r++) {
        const int col = n0 + wc * 64 + ni * 16 + lc;
        float v = acc[mi][ni][r];
        if (MODE == 0) {
          v = (v + bias[col]) * ((col >> 10) == 0 ? scale : 1.0f);
        } else {
          v = 0.5f * v * (1.0f + erff(v * 0.70710678118654752440f));
        }
        Es[wr * 2048 + (g * 4 + r) * 128 + wc * 64 + ni * 16 + lc] = f2bf(v);
      }
    }
    __syncthreads();
    {
      const int rr = t >> 3;
      const int wr2 = rr >> 4, r16 = rr & 15;
      const int cc = (t & 7) * 16;
      short8 o0 = *(short8*)&Es[wr2 * 2048 + r16 * 128 + cc];
      short8 o1 = *(short8*)&Es[wr2 * 2048 + r16 * 128 + cc + 8];
      const int row = m0 + wr2 * 64 + mi * 16 + r16;
      if (MODE == 0) {
        const int col0 = n0 + cc;
        const int which = col0 >> 10, c = col0 & 1023;
        const int hh = c >> 6, dk = c & 63;
        const int b = row >> 10, pos = row & 1023;
        u16* dst = outB + (size_t)which * 4194304 +
                   (((size_t)(b * 16 + hh)) * 1024 + pos) * 64 + dk;
        *(short8*)dst = o0;
        *(short8*)(dst + 8) = o1;
      } else {
        u16* dst = outB + (size_t)row * (size_t)N + n0 + cc;
        *(short8*)dst = o0;
        *(short8*)(dst + 8) = o1;
      }
    }
    __syncthreads();
  }
}

// ---------- GEMM 64x128 tile (FC / FFN2: 512 blocks = 2/CU) + XCD swizzle ----------
template<int MODE>
__global__ __launch_bounds__(256, 4) void gemm_nt64(
    const u16* __restrict__ A, const u16* __restrict__ Bw,
    int M, int N, int K,
    const float* __restrict__ bias, const float* __restrict__ res,
    float* __restrict__ outF) {
  __shared__ u16 As[3][2048];
  __shared__ u16 Bs[3][4096];
  const int t = threadIdx.x;
  const int w = t >> 6, lane = t & 63;
  const int wr = w >> 1, wc = w & 1;
  const int g = lane >> 4, lc = lane & 15;

  const int nwg = gridDim.x * gridDim.y;
  const int flat = xcd_swz(blockIdx.y * gridDim.x + blockIdx.x, nwg);
  const int bx = flat % gridDim.x, by = flat / gridDim.x;
  const int m0 = by * 64, n0 = bx * 128;

  const int srow = w * 16 + (lane >> 2);
  const int sc8  = (lane & 3) ^ ((srow >> 1) & 3);
  const u16* Ag = &A[(size_t)(m0 + srow) * K + sc8 * 8];
  const u16* Bg = &Bw[(size_t)(n0 + srow) * K + sc8 * 8];
  const size_t row64 = (size_t)64 * K;
  const int swz = (lc >> 1) & 3;

  const int NT = K >> 5;
  f32x4 acc[2][4] = {};

  auto stage = [&](int buf, int tt) {
    const int k0 = tt << 5;
    gload16(Ag + k0, &As[buf][w * 512]);
    gload16(Bg + k0, &Bs[buf][w * 512]);
    gload16(Bg + row64 + k0, &Bs[buf][w * 512 + 2048]);
  };

  stage(0, 0);
  stage(1, 1);

  for (int tt = 0; tt < NT; tt++) {
    const int cur = tt % 3;
    if (tt < NT - 1) {
      asm volatile("s_waitcnt vmcnt(3)" ::: "memory");
    } else {
      asm volatile("s_waitcnt vmcnt(0)" ::: "memory");
    }
    __builtin_amdgcn_s_barrier();
    if (tt + 2 < NT) stage((tt + 2) % 3, tt + 2);   // issue loads early
    short8 af[2], bf[4];
#pragma unroll
    for (int mi = 0; mi < 2; mi++)
      af[mi] = *(short8*)&As[cur][(wr * 32 + mi * 16 + lc) * 32 + (g ^ swz) * 8];
#pragma unroll
    for (int ni = 0; ni < 4; ni++)
      bf[ni] = *(short8*)&Bs[cur][(wc * 64 + ni * 16 + lc) * 32 + (g ^ swz) * 8];
#pragma unroll
    for (int mi = 0; mi < 2; mi++)
#pragma unroll
      for (int ni = 0; ni < 4; ni++)
        acc[mi][ni] = __builtin_amdgcn_mfma_f32_16x16x32_bf16(af[mi], bf[ni], acc[mi][ni], 0, 0, 0);
  }

#pragma unroll
  for (int mi = 0; mi < 2; mi++) {
#pragma unroll
    for (int ni = 0; ni < 4; ni++) {
#pragma unroll
      for (int r = 0; r < 4; r++) {
        const int row = m0 + wr * 32 + mi * 16 + g * 4 + r;
        const int col = n0 + wc * 64 + ni * 16 + lc;
        float v = acc[mi][ni][r];
        if (MODE == 1) {
          v += bias[col] + res[(size_t)row * 1024 + col];
        } else {
          v += res[(size_t)row * 1024 + col];
        }
        outF[(size_t)row * 1024 + col] = v;
      }
    }
  }
}

// ---------- flash attention: ctx + (m,l) + fused position_bias writer ----------
// tabs kept UNSCALED in LDS (pb needs exact values); L2E folded into the
// score add via fmaf. Per tile-iteration, 4 pb rows stored (coalesced float4,
// spread across the loop -> overlaps MFMA/softmax compute).
__global__ __launch_bounds__(256) void attn_kernel(
    const u16* __restrict__ q, const u16* __restrict__ k,
    const u16* __restrict__ vt, const float* __restrict__ tab,
    u16* __restrict__ ctx, float* __restrict__ ml, float* __restrict__ pb) {
  const int flat = xcd_swz(blockIdx.y * 16 + blockIdx.x, 1024);
  const int bh = flat / 16;
  const int i0 = (flat % 16) * 64;
  const int h = bh & 15, b = bh >> 4;
  const int t = threadIdx.x, w = t >> 6, lane = t & 63;
  const int g = lane >> 4, lc = lane & 15;
  const int sr = t >> 3;
  const int swc = ((t & 7) ^ (sr & 7)) * 8;
  const int sc = (t & 7) * 8;

  __shared__ u16 Ks[2][64][64];
  __shared__ u16 Vts[2][64][64];
  __shared__ u16 P[4][16][64];
  __shared__ float tabs[2048];

  const u16* qb  = q + (size_t)bh * 65536;
  const u16* kb  = k + (size_t)bh * 65536;
  const u16* vtb = vt + (size_t)bh * 65536;

  // hoist full bias row for this head into LDS (UNSCALED)
  ((float4*)tabs)[t]       = ((const float4*)(tab + h * 2048))[t];
  ((float4*)tabs)[t + 256] = ((const float4*)(tab + h * 2048))[t + 256];

  const short8 aq0 = *(const short8*)&qb[(size_t)(i0 + w * 16 + lc) * 64 + g * 8];
  const short8 aq1 = *(const short8*)&qb[(size_t)(i0 + w * 16 + lc) * 64 + 32 + g * 8];

  {
    short8 ka = *(const short8*)&kb[(size_t)sr * 64 + sc];
    short8 kc = *(const short8*)&kb[(size_t)(sr + 32) * 64 + sc];
    short8 va = *(const short8*)&vtb[(size_t)sr * 1024 + sc];
    short8 vc = *(const short8*)&vtb[(size_t)(sr + 32) * 1024 + sc];
    *(short8*)&Ks[0][sr][swc]       = ka;
    *(short8*)&Ks[0][sr + 32][swc]  = kc;
    *(short8*)&Vts[0][sr][swc]      = va;
    *(short8*)&Vts[0][sr + 32][swc] = vc;
  }
  __syncthreads();

  const int rx = lc & 7;
  const int ibase = 1024 - i0 - (w * 16 + g * 4) + lc;
  float* pbrow = pb + (size_t)bh * 1048576 + (size_t)i0 * 1024 + t * 4;

  float m_r[4] = {-INFINITY, -INFINITY, -INFINITY, -INFINITY};
  float l_r[4] = {0.f, 0.f, 0.f, 0.f};
  f32x4 cacc[4] = {};

  for (int tt = 0; tt < 16; tt++) {
    const int buf = tt & 1;
    const int j0 = tt * 64;

    short8 nka, nkc, nva, nvc;
    if (tt < 15) {
      const int jn = j0 + 64;
      nka = *(const short8*)&kb[(size_t)(jn + sr) * 64 + sc];
      nkc = *(const short8*)&kb[(size_t)(jn + sr + 32) * 64 + sc];
      nva = *(const short8*)&vtb[(size_t)sr * 1024 + jn + sc];
      nvc = *(const short8*)&vtb[(size_t)(sr + 32) * 1024 + jn + sc];
    }

    f32x4 s[4] = {};
#pragma unroll
    for (int ni = 0; ni < 4; ni++) {
      short8 b0 = *(short8*)&Ks[buf][ni * 16 + lc][(g ^ rx) * 8];
      short8 b1 = *(short8*)&Ks[buf][ni * 16 + lc][((4 + g) ^ rx) * 8];
      s[ni] = __builtin_amdgcn_mfma_f32_16x16x32_bf16(aq0, b0, s[ni], 0, 0, 0);
      s[ni] = __builtin_amdgcn_mfma_f32_16x16x32_bf16(aq1, b1, s[ni], 0, 0, 0);
    }
#pragma unroll
    for (int ni = 0; ni < 4; ni++)
#pragma unroll
      for (int r = 0; r < 4; r++)
        s[ni][r] = fmaf(tabs[ibase + j0 + ni * 16 - r], L2E, s[ni][r]);

#pragma unroll
    for (int r = 0; r < 4; r++) {
      float tm = fmaxf(fmaxf(s[0][r], s[1][r]), fmaxf(s[2][r], s[3][r]));
#pragma unroll
      for (int off = 1; off < 16; off <<= 1) tm = fmaxf(tm, __shfl_xor(tm, off, 64));
      const float mn = fmaxf(m_r[r], tm);
      const float scl = __builtin_amdgcn_exp2f(m_r[r] - mn);
      float rs = 0.f;
#pragma unroll
      for (int ni = 0; ni < 4; ni++) {
        float p = __builtin_amdgcn_exp2f(s[ni][r] - mn);
        s[ni][r] = p;
        rs += p;
      }
#pragma unroll
      for (int off = 1; off < 16; off <<= 1) rs += __shfl_xor(rs, off, 64);
      l_r[r] = l_r[r] * scl + rs;
      m_r[r] = mn;
#pragma unroll
      for (int d = 0; d < 4; d++) cacc[d][r] *= scl;
    }

#pragma unroll
    for (int ni = 0; ni < 4; ni++)
#pragma unroll
      for (int r = 0; r < 4; r++) {
        const int prow = g * 4 + r;
        P[w][prow][(((ni * 2 + (lc >> 3)) ^ (prow & 7)) << 3) | (lc & 7)] = f2bf(s[ni][r]);
      }

    short8 ap0 = *(short8*)&P[w][lc][(g ^ rx) * 8];
    short8 ap1 = *(short8*)&P[w][lc][((4 + g) ^ rx) * 8];
#pragma unroll
    for (int d = 0; d < 4; d++) {
      short8 bv0 = *(short8*)&Vts[buf][d * 16 + lc][(g ^ rx) * 8];
      short8 bv1 = *(short8*)&Vts[buf][d * 16 + lc][((4 + g) ^ rx) * 8];
      cacc[d] = __builtin_amdgcn_mfma_f32_16x16x32_bf16(ap0, bv0, cacc[d], 0, 0, 0);
      cacc[d] = __builtin_amdgcn_mfma_f32_16x16x32_bf16(ap1, bv1, cacc[d], 0, 0, 0);
    }

    // ---- fused pb writer: 4 rows per iteration, values from LDS tabs ----
    {
#pragma unroll
      for (int r4 = 0; r4 < 4; r4++) {
        const int il = tt * 4 + r4;          // local row 0..63
        const int base = t * 4 - (i0 + il) + 1024;
        float4 o;
        o.x = tabs[base + 0];
        o.y = tabs[base + 1];
        o.z = tabs[base + 2];
        o.w = tabs[base + 3];
        *(float4*)&pbrow[(size_t)il * 1024] = o;
      }
    }

    if (tt < 15) {
      *(short8*)&Ks[buf ^ 1][sr][swc]       = nka;
      *(short8*)&Ks[buf ^ 1][sr + 32][swc]  = nkc;
      *(short8*)&Vts[buf ^ 1][sr][swc]      = nva;
      *(short8*)&Vts[buf ^ 1][sr + 32][swc] = nvc;
    }
    __syncthreads();
  }

  float inv[4];
#pragma unroll
  for (int r = 0; r < 4; r++) inv[r] = 1.0f / l_r[r];
#pragma unroll
  for (int d = 0; d < 4; d++)
#pragma unroll
    for (int r = 0; r < 4; r++) {
      const int pos = i0 + w * 16 + g * 4 + r;
      ctx[((size_t)b * 1024 + pos) * 1024 + h * 64 + d * 16 + lc] = f2bf(cacc[d][r] * inv[r]);
    }
  if (lc == 0) {
#pragma unroll
    for (int r = 0; r < 4; r++) {
      const int i = i0 + w * 16 + g * 4 + r;
      ml[(size_t)bh * 1024 + i] = m_r[r];
      ml[65536 + (size_t)bh * 1024 + i] = l_r[r];
    }
  }
}

// ---------- attn_sum: recompute scores (exp2 domain), sum over heads ----------
__global__ __launch_bounds__(256) void attn_sum_kernel(
    const u16* __restrict__ q, const u16* __restrict__ k,
    const float* __restrict__ tab, const float* __restrict__ ml,
    float* __restrict__ asum) {
  const int flat = xcd_swz(((blockIdx.z * 16 + blockIdx.y) * 16) + blockIdx.x, 1024);
  const int j0 = (flat % 16) * 64;
  const int i0 = ((flat / 16) % 16) * 64;
  const int b = flat / 256;
  const int t = threadIdx.x, w = t >> 6, lane = t & 63;
  const int g = lane >> 4, lc = lane & 15;
  const int sr = t >> 3;
  const int swc = ((t & 7) ^ (sr & 7)) * 8;
  const int sc = (t & 7) * 8;
  const int rx = lc & 7;
  __shared__ u16 Ks[64][64];
  __shared__ float tabs[128];

  f32x4 acc[4] = {};

  for (int h = 0; h < 16; h++) {
    const int bh = b * 16 + h;
    __syncthreads();
    const u16* kb = k + (size_t)bh * 65536;
    *(short8*)&Ks[sr][swc]      = *(const short8*)&kb[(size_t)(j0 + sr) * 64 + sc];
    *(short8*)&Ks[sr + 32][swc] = *(const short8*)&kb[(size_t)(j0 + sr + 32) * 64 + sc];
    if (t < 127) tabs[t] = tab[h * 2048 + (j0 - i0 - 63 + t) + 1024] * L2E;
    __syncthreads();
    const u16* qb = q + (size_t)bh * 65536;
    short8 aq0 = *(const short8*)&qb[(size_t)(i0 + w * 16 + lc) * 64 + g * 8];
    short8 aq1 = *(const short8*)&qb[(size_t)(i0 + w * 16 + lc) * 64 + 32 + g * 8];
    f32x4 s[4] = {};
#pragma unroll
    for (int ni = 0; ni < 4; ni++) {
      short8 b0 = *(short8*)&Ks[ni * 16 + lc][(g ^ rx) * 8];
      short8 b1 = *(short8*)&Ks[ni * 16 + lc][((4 + g) ^ rx) * 8];
      s[ni] = __builtin_amdgcn_mfma_f32_16x16x32_bf16(aq0, b0, s[ni], 0, 0, 0);
      s[ni] = __builtin_amdgcn_mfma_f32_16x16x32_bf16(aq1, b1, s[ni], 0, 0, 0);
    }
    float mm[4], li[4];
#pragma unroll
    for (int r = 0; r < 4; r++) {
      const int i = i0 + w * 16 + g * 4 + r;
      mm[r] = ml[(size_t)bh * 1024 + i];
      li[r] = 1.0f / ml[65536 + (size_t)bh * 1024 + i];
    }
#pragma unroll
    for (int ni = 0; ni < 4; ni++)
#pragma unroll
      for (int r = 0; r < 4; r++) {
        float sv = s[ni][r] + tabs[ni * 16 + lc - w * 16 - g * 4 - r + 63];
        acc[ni][r] += __builtin_amdgcn_exp2f(sv - mm[r]) * li[r];
      }
  }
#pragma unroll
  for (int ni = 0; ni < 4; ni++)
#pragma unroll
    for (int r = 0; r < 4; r++) {
      const int i = i0 + w * 16 + g * 4 + r;
      asum[((size_t)b * 1024 + i) * 1024 + j0 + ni * 16 + lc] = acc[ni][r];
    }
}

// ---------- launch ----------
extern "C" void kernel_launch(void* const* d_in, const int* in_sizes, int n_in,
                              void* d_out, int out_size, void* d_ws, size_t ws_size,
                              hipStream_t stream) {
  const float* src      = (const float*)d_in[0];
  const float* ln1_w    = (const float*)d_in[2];
  const float* wq       = (const float*)d_in[3];
  const float* bq       = (const float*)d_in[4];
  const float* wk       = (const float*)d_in[5];
  const float* bk       = (const float*)d_in[6];
  const float* wv       = (const float*)d_in[7];
  const float* bv       = (const float*)d_in[8];
  const float* fc_w     = (const float*)d_in[9];
  const float* fc_b     = (const float*)d_in[10];
  const float* rel_bias = (const float*)d_in[11];
  const float* ln2_w    = (const float*)d_in[12];
  const float* wi       = (const float*)d_in[13];
  const float* wo       = (const float*)d_in[14];

  const size_t MB = 1u << 20;
  char* ws = (char*)d_ws;
  u16* wq_b   = (u16*)(ws + 0 * MB);     // wq/wk/wv contiguous = fused [3072][1024]
  u16* wk_b   = (u16*)(ws + 2 * MB);
  u16* wv_b   = (u16*)(ws + 4 * MB);
  u16* fcw_b  = (u16*)(ws + 6 * MB);
  u16* wi_b   = (u16*)(ws + 8 * MB);
  u16* wo_b   = (u16*)(ws + 16 * MB);
  u16* proj_b = (u16*)(ws + 24 * MB);   // reused as nx
  u16* q_b    = (u16*)(ws + 32 * MB);   // q/k/v contiguous, 4M u16 apart
  u16* k_b    = (u16*)(ws + 40 * MB);
  u16* v_b    = (u16*)(ws + 48 * MB);
  u16* vt_b   = (u16*)(ws + 56 * MB);
  u16* h_b    = (u16*)(ws + 32 * MB);   // aliases q/k/v/vt (dead by then)
  u16* ctx_b  = (u16*)(ws + 64 * MB);
  float* attn_out = (float*)(ws + 72 * MB);
  float* ml   = (float*)(ws + 88 * MB);
  float* tab  = (float*)(ws + 88 * MB + 512 * 1024);
  float* fb   = (float*)(ws + 90 * MB);

  float* outF = (float*)d_out;
  float* asum = outF + 4194304;
  float* pb   = outF + 8388608;

  prep<<<12428, 256, 0, stream>>>(wq, wk, wv, fc_w, wi, wo, bq, bk, bv, rel_bias,
                                  wq_b, wk_b, wv_b, fcw_b, wi_b, wo_b, fb, tab);

  t5_ln<<<4096, 256, 0, stream>>>(src, ln1_w, 1e-12f, proj_b);

  // fused QKV: 128x128 tiles, 768 blocks = exactly 3 rounds at 3/CU
  gemm_nt<0><<<dim3(24, 32), 256, 0, stream>>>(proj_b, wq_b, 4096, 3072, 1024, fb, nullptr,
                                               0.125f * L2E, nullptr, q_b);

  transpose_v<<<dim3(16, 64), 256, 0, stream>>>(v_b, vt_b);
  // attn + fused position_bias writer
  attn_kernel<<<dim3(16, 64), 256, 0, stream>>>(q_b, k_b, vt_b, tab, ctx_b, ml, pb);
  attn_sum_kernel<<<dim3(16, 16, 4), 256, 0, stream>>>(q_b, k_b, tab, ml, asum);

  // FC: 64x128 tile -> 512 blocks = 2/CU
  gemm_nt64<1><<<dim3(8, 64), 256, 0, stream>>>(ctx_b, fcw_b, 4096, 1024, 1024, fc_b, src, attn_out);

  t5_ln<<<4096, 256, 0, stream>>>(attn_out, ln2_w, 1e-6f, proj_b);

  // FFN1: 128x128 tiles
  gemm_nt<2><<<dim3(32, 32), 256, 0, stream>>>(proj_b, wi_b, 4096, 4096, 1024, nullptr, nullptr,
                                               1.0f, nullptr, h_b);
  // FFN2: 64x128 tile -> 512 blocks = 2/CU
  gemm_nt64<3><<<dim3(8, 64), 256, 0, stream>>>(h_b, wo_b, 4096, 1024, 4096, nullptr, attn_out, outF);
}

// Round 14
// 321.407 us; speedup vs baseline: 1.1213x; 1.0260x over previous
//
#include <hip/hip_runtime.h>
#include <hip/hip_bf16.h>
#include <math.h>

typedef __attribute__((ext_vector_type(8))) short short8;
typedef __attribute__((ext_vector_type(4))) float f32x4;
typedef unsigned short u16;

#define L2E 1.44269504088896340736f

// ---------- helpers ----------
__device__ __forceinline__ u16 f2bf(float f) {
  union { float f; unsigned u; } x; x.f = f;
  unsigned r = x.u + 0x7fffu + ((x.u >> 16) & 1u);   // RNE
  return (u16)(r >> 16);
}

__device__ __forceinline__ void gload16(const void* g, void* l) {
  auto gp = reinterpret_cast<const __attribute__((address_space(1))) void*>(
      reinterpret_cast<uintptr_t>(g));
  auto lp = reinterpret_cast<__attribute__((address_space(3))) void*>(
      reinterpret_cast<uintptr_t>(l));
  __builtin_amdgcn_global_load_lds(gp, lp, 16, 0, 0);
}

// XCD-aware chunked remap (T1). Requires nwg % 8 == 0 (bijective).
__device__ __forceinline__ int xcd_swz(int flat, int nwg) {
  return (flat & 7) * (nwg >> 3) + (flat >> 3);
}

// exact T5 bucket: matches floor(2*log2(n/8)) with integer arithmetic
__device__ __forceinline__ int bucket_fn(int rel) {
  int n = -rel;              // i - j
  int ret = 0;
  if (n < 0) { ret = 16; n = -n; }
  if (n < 8) return ret + n;
  int e = 31 - __clz(n);
  unsigned nn = (unsigned)n * (unsigned)n;
  int f = 2 * e + ((nn >= (1u << (2 * e + 1))) ? 1 : 0) - 6;
  int val = 8 + f;
  if (val > 15) val = 15;
  return ret + val;
}

// ---------- fused prep + first T5-LN (independent work, block-partitioned) ----------
__global__ __launch_bounds__(256) void prep_ln(
    const float* __restrict__ wq, const float* __restrict__ wk,
    const float* __restrict__ wv, const float* __restrict__ fcw,
    const float* __restrict__ wi, const float* __restrict__ wo,
    const float* __restrict__ bq, const float* __restrict__ bk,
    const float* __restrict__ bv, const float* __restrict__ rel_bias,
    u16* __restrict__ wqb, u16* __restrict__ wkb, u16* __restrict__ wvb,
    u16* __restrict__ fcwb, u16* __restrict__ wib, u16* __restrict__ wob,
    float* __restrict__ fb, float* __restrict__ tab,
    const float* __restrict__ src, const float* __restrict__ ln1_w,
    u16* __restrict__ proj) {
  const int blk = blockIdx.x, t = threadIdx.x;
  if (blk < 12288) {
    const float* s; u16* d; int rel;
    if (blk < 1024)      { s = wq;  d = wqb;  rel = blk; }
    else if (blk < 2048) { s = wk;  d = wkb;  rel = blk - 1024; }
    else if (blk < 3072) { s = wv;  d = wvb;  rel = blk - 2048; }
    else if (blk < 4096) { s = fcw; d = fcwb; rel = blk - 3072; }
    else if (blk < 8192) { s = wi;  d = wib;  rel = blk - 4096; }
    else                 { s = wo;  d = wob;  rel = blk - 8192; }
    const int i = (rel * 256 + t) * 4;
    float4 v = *(const float4*)&s[i];
    d[i + 0] = f2bf(v.x); d[i + 1] = f2bf(v.y);
    d[i + 2] = f2bf(v.z); d[i + 3] = f2bf(v.w);
  } else if (blk < 12300) {
    const int i = (blk - 12288) * 256 + t;   // 3072
    fb[i] = i < 1024 ? bq[i] : (i < 2048 ? bk[i - 1024] : bv[i - 2048]);
  } else if (blk < 12428) {
    const int idx = (blk - 12300) * 256 + t; // 16*2048
    const int h = idx >> 11;
    const int rel = (idx & 2047) - 1024;
    tab[idx] = rel_bias[bucket_fn(rel) * 16 + h];
  } else {
    // T5 layernorm of src (eps 1e-12)
    const int row = blk - 12428;
    const float4 v = ((const float4*)(src + (size_t)row * 1024))[t];
    float ss = v.x * v.x + v.y * v.y + v.z * v.z + v.w * v.w;
#pragma unroll
    for (int off = 1; off < 64; off <<= 1) ss += __shfl_xor(ss, off, 64);
    __shared__ float red[4];
    if ((t & 63) == 0) red[t >> 6] = ss;
    __syncthreads();
    float tot = red[0] + red[1] + red[2] + red[3];
    float inv = 1.0f / sqrtf(tot * (1.0f / 1024.0f) + 1e-12f);
    const float4 wv = ((const float4*)ln1_w)[t];
    u16* o = proj + (size_t)row * 1024 + t * 4;
    o[0] = f2bf(v.x * inv * wv.x);
    o[1] = f2bf(v.y * inv * wv.y);
    o[2] = f2bf(v.z * inv * wv.z);
    o[3] = f2bf(v.w * inv * wv.w);
  }
}

__global__ __launch_bounds__(256) void t5_ln(const float* __restrict__ x,
                                             const float* __restrict__ wgt,
                                             float eps, u16* __restrict__ out) {
  const int row = blockIdx.x, t = threadIdx.x;
  const float4 v = ((const float4*)(x + (size_t)row * 1024))[t];
  float ss = v.x * v.x + v.y * v.y + v.z * v.z + v.w * v.w;
#pragma unroll
  for (int off = 1; off < 64; off <<= 1) ss += __shfl_xor(ss, off, 64);
  __shared__ float red[4];
  if ((t & 63) == 0) red[t >> 6] = ss;
  __syncthreads();
  float tot = red[0] + red[1] + red[2] + red[3];
  float inv = 1.0f / sqrtf(tot * (1.0f / 1024.0f) + eps);
  const float4 wv = ((const float4*)wgt)[t];
  u16* o = out + (size_t)row * 1024 + t * 4;
  o[0] = f2bf(v.x * inv * wv.x);
  o[1] = f2bf(v.y * inv * wv.y);
  o[2] = f2bf(v.z * inv * wv.z);
  o[3] = f2bf(v.w * inv * wv.w);
}

__global__ __launch_bounds__(256) void transpose_v(const u16* __restrict__ v,
                                                   u16* __restrict__ vt) {
  __shared__ u16 T[64][72];
  const int bh = blockIdx.y;
  const int l0 = blockIdx.x * 64;
  const int t = threadIdx.x;
  const int sr = t >> 3, sc = (t & 7) * 8;
  const u16* vb = v + (size_t)bh * 65536;
  *(short8*)&T[sr][sc]      = *(const short8*)&vb[(size_t)(l0 + sr) * 64 + sc];
  *(short8*)&T[sr + 32][sc] = *(const short8*)&vb[(size_t)(l0 + sr + 32) * 64 + sc];
  __syncthreads();
  u16* vtb = vt + (size_t)bh * 65536;
  short8 o0, o1;
#pragma unroll
  for (int u = 0; u < 8; u++) {
    ((u16*)&o0)[u] = T[sc + u][sr];
    ((u16*)&o1)[u] = T[sc + u][sr + 32];
  }
  *(short8*)&vtb[(size_t)sr * 1024 + l0 + sc]        = o0;
  *(short8*)&vtb[(size_t)(sr + 32) * 1024 + l0 + sc] = o1;
}

// ---------- GEMM 128x128: bf16 out via LDS epilogue + XCD swizzle ----------
// MODE 0: (acc+fb[col])*sel_scale -> bf16 permuted [b,h,pos,dk], QKV fused (N=3072)
// MODE 2: gelu(acc) -> bf16 row-major
template<int MODE>
__global__ __launch_bounds__(256, 3) void gemm_nt(
    const u16* __restrict__ A, const u16* __restrict__ Bw,
    int M, int N, int K,
    const float* __restrict__ bias, const float* __restrict__ res,
    float scale, float* __restrict__ outF, u16* __restrict__ outB) {
  __shared__ u16 As[3][4096];
  __shared__ u16 Bs[3][4096];
  const int t = threadIdx.x;
  const int w = t >> 6, lane = t & 63;
  const int wr = w >> 1, wc = w & 1;
  const int g = lane >> 4, lc = lane & 15;

  const int nwg = gridDim.x * gridDim.y;
  const int flat = xcd_swz(blockIdx.y * gridDim.x + blockIdx.x, nwg);
  const int bx = flat % gridDim.x, by = flat / gridDim.x;
  const int m0 = by * 128, n0 = bx * 128;

  const int srow = w * 16 + (lane >> 2);
  const int sc8  = (lane & 3) ^ ((srow >> 1) & 3);
  const u16* Ag = &A[(size_t)(m0 + srow) * K + sc8 * 8];
  const u16* Bg = &Bw[(size_t)(n0 + srow) * K + sc8 * 8];
  const size_t row64 = (size_t)64 * K;
  const int swz = (lc >> 1) & 3;

  const int NT = K >> 5;
  f32x4 acc[4][4] = {};

  auto stage = [&](int buf, int tt) {
    const int k0 = tt << 5;
    u16* lA = &As[buf][w * 512];
    u16* lB = &Bs[buf][w * 512];
    gload16(Ag + k0, lA);
    gload16(Ag + row64 + k0, lA + 2048);
    gload16(Bg + k0, lB);
    gload16(Bg + row64 + k0, lB + 2048);
  };

  stage(0, 0);
  stage(1, 1);

  for (int tt = 0; tt < NT; tt++) {
    const int cur = tt % 3;
    if (tt < NT - 1) {
      asm volatile("s_waitcnt vmcnt(4)" ::: "memory");
    } else {
      asm volatile("s_waitcnt vmcnt(0)" ::: "memory");
    }
    __builtin_amdgcn_s_barrier();
    if (tt + 2 < NT) stage((tt + 2) % 3, tt + 2);   // issue loads early
    short8 af[4], bf[4];
#pragma unroll
    for (int mi = 0; mi < 4; mi++)
      af[mi] = *(short8*)&As[cur][(wr * 64 + mi * 16 + lc) * 32 + (g ^ swz) * 8];
#pragma unroll
    for (int ni = 0; ni < 4; ni++)
      bf[ni] = *(short8*)&Bs[cur][(wc * 64 + ni * 16 + lc) * 32 + (g ^ swz) * 8];
#pragma unroll
    for (int mi = 0; mi < 4; mi++)
#pragma unroll
      for (int ni = 0; ni < 4; ni++)
        acc[mi][ni] = __builtin_amdgcn_mfma_f32_16x16x32_bf16(af[mi], bf[ni], acc[mi][ni], 0, 0, 0);
  }

  // ---- epilogue: per-mi re-layout through LDS -> coalesced 16B stores ----
  u16* Es = &As[0][0];
  __syncthreads();
#pragma unroll
  for (int mi = 0; mi < 4; mi++) {
#pragma unroll
    for (int ni = 0; ni < 4; ni++) {
#pragma unroll
      for (int r = 0; r < 4; r++) {
        const int col = n0 + wc * 64 + ni * 16 + lc;
        float v = acc[mi][ni][r];
        if (MODE == 0) {
          v = (v + bias[col]) * ((col >> 10) == 0 ? scale : 1.0f);
        } else {
          v = 0.5f * v * (1.0f + erff(v * 0.70710678118654752440f));
        }
        Es[wr * 2048 + (g * 4 + r) * 128 + wc * 64 + ni * 16 + lc] = f2bf(v);
      }
    }
    __syncthreads();
    {
      const int rr = t >> 3;
      const int wr2 = rr >> 4, r16 = rr & 15;
      const int cc = (t & 7) * 16;
      short8 o0 = *(short8*)&Es[wr2 * 2048 + r16 * 128 + cc];
      short8 o1 = *(short8*)&Es[wr2 * 2048 + r16 * 128 + cc + 8];
      const int row = m0 + wr2 * 64 + mi * 16 + r16;
      if (MODE == 0) {
        const int col0 = n0 + cc;
        const int which = col0 >> 10, c = col0 & 1023;
        const int hh = c >> 6, dk = c & 63;
        const int b = row >> 10, pos = row & 1023;
        u16* dst = outB + (size_t)which * 4194304 +
                   (((size_t)(b * 16 + hh)) * 1024 + pos) * 64 + dk;
        *(short8*)dst = o0;
        *(short8*)(dst + 8) = o1;
      } else {
        u16* dst = outB + (size_t)row * (size_t)N + n0 + cc;
        *(short8*)dst = o0;
        *(short8*)(dst + 8) = o1;
      }
    }
    __syncthreads();
  }
}

// ---------- GEMM 64x128 tile (FFN2: 512 blocks = 2/CU) + XCD swizzle ----------
template<int MODE>
__global__ __launch_bounds__(256, 4) void gemm_nt64(
    const u16* __restrict__ A, const u16* __restrict__ Bw,
    int M, int N, int K,
    const float* __restrict__ bias, const float* __restrict__ res,
    float* __restrict__ outF) {
  __shared__ u16 As[3][2048];
  __shared__ u16 Bs[3][4096];
  const int t = threadIdx.x;
  const int w = t >> 6, lane = t & 63;
  const int wr = w >> 1, wc = w & 1;
  const int g = lane >> 4, lc = lane & 15;

  const int nwg = gridDim.x * gridDim.y;
  const int flat = xcd_swz(blockIdx.y * gridDim.x + blockIdx.x, nwg);
  const int bx = flat % gridDim.x, by = flat / gridDim.x;
  const int m0 = by * 64, n0 = bx * 128;

  const int srow = w * 16 + (lane >> 2);
  const int sc8  = (lane & 3) ^ ((srow >> 1) & 3);
  const u16* Ag = &A[(size_t)(m0 + srow) * K + sc8 * 8];
  const u16* Bg = &Bw[(size_t)(n0 + srow) * K + sc8 * 8];
  const size_t row64 = (size_t)64 * K;
  const int swz = (lc >> 1) & 3;

  const int NT = K >> 5;
  f32x4 acc[2][4] = {};

  auto stage = [&](int buf, int tt) {
    const int k0 = tt << 5;
    gload16(Ag + k0, &As[buf][w * 512]);
    gload16(Bg + k0, &Bs[buf][w * 512]);
    gload16(Bg + row64 + k0, &Bs[buf][w * 512 + 2048]);
  };

  stage(0, 0);
  stage(1, 1);

  for (int tt = 0; tt < NT; tt++) {
    const int cur = tt % 3;
    if (tt < NT - 1) {
      asm volatile("s_waitcnt vmcnt(3)" ::: "memory");
    } else {
      asm volatile("s_waitcnt vmcnt(0)" ::: "memory");
    }
    __builtin_amdgcn_s_barrier();
    if (tt + 2 < NT) stage((tt + 2) % 3, tt + 2);   // issue loads early
    short8 af[2], bf[4];
#pragma unroll
    for (int mi = 0; mi < 2; mi++)
      af[mi] = *(short8*)&As[cur][(wr * 32 + mi * 16 + lc) * 32 + (g ^ swz) * 8];
#pragma unroll
    for (int ni = 0; ni < 4; ni++)
      bf[ni] = *(short8*)&Bs[cur][(wc * 64 + ni * 16 + lc) * 32 + (g ^ swz) * 8];
#pragma unroll
    for (int mi = 0; mi < 2; mi++)
#pragma unroll
      for (int ni = 0; ni < 4; ni++)
        acc[mi][ni] = __builtin_amdgcn_mfma_f32_16x16x32_bf16(af[mi], bf[ni], acc[mi][ni], 0, 0, 0);
  }

#pragma unroll
  for (int mi = 0; mi < 2; mi++) {
#pragma unroll
    for (int ni = 0; ni < 4; ni++) {
#pragma unroll
      for (int r = 0; r < 4; r++) {
        const int row = m0 + wr * 32 + mi * 16 + g * 4 + r;
        const int col = n0 + wc * 64 + ni * 16 + lc;
        float v = acc[mi][ni][r];
        if (MODE == 1) {
          v += bias[col] + res[(size_t)row * 1024 + col];
        } else {
          v += res[(size_t)row * 1024 + col];
        }
        outF[(size_t)row * 1024 + col] = v;
      }
    }
  }
}

// ---------- fused FC + attn_sum (mutually independent; block-partitioned) ----------
// blocks 0..511: FC (64x128 GEMM, acc+bias+res->f32)
// blocks 512..1535: attn_sum (recompute scores exp2-domain, sum over heads)
__global__ __launch_bounds__(256, 3) void fc_asum(
    const u16* __restrict__ ctx, const u16* __restrict__ fcw,
    const float* __restrict__ fc_b, const float* __restrict__ src,
    float* __restrict__ attn_out,
    const u16* __restrict__ q, const u16* __restrict__ k,
    const float* __restrict__ tab, const float* __restrict__ ml,
    float* __restrict__ asum) {
  __shared__ char pool[36864];
  const int t = threadIdx.x;
  const int w = t >> 6, lane = t & 63;
  const int g = lane >> 4, lc = lane & 15;

  if (blockIdx.x < 512) {
    // ================= FC branch =================
    u16* As = (u16*)pool;                 // [3][2048]
    u16* Bs = (u16*)(pool + 12288);       // [3][4096]
    const int wr = w >> 1, wc = w & 1;
    const int flat = xcd_swz(blockIdx.x, 512);
    const int bx = flat & 7, by = flat >> 3;
    const int m0 = by * 64, n0 = bx * 128;
    const int K = 1024;

    const int srow = w * 16 + (lane >> 2);
    const int sc8  = (lane & 3) ^ ((srow >> 1) & 3);
    const u16* Ag = &ctx[(size_t)(m0 + srow) * K + sc8 * 8];
    const u16* Bg = &fcw[(size_t)(n0 + srow) * K + sc8 * 8];
    const size_t row64 = (size_t)64 * K;
    const int swz = (lc >> 1) & 3;

    const int NT = K >> 5;
    f32x4 acc[2][4] = {};

    auto stage = [&](int buf, int tt) {
      const int k0 = tt << 5;
      gload16(Ag + k0, &As[buf * 2048 + w * 512]);
      gload16(Bg + k0, &Bs[buf * 4096 + w * 512]);
      gload16(Bg + row64 + k0, &Bs[buf * 4096 + w * 512 + 2048]);
    };

    stage(0, 0);
    stage(1, 1);

    for (int tt = 0; tt < NT; tt++) {
      const int cur = tt % 3;
      if (tt < NT - 1) {
        asm volatile("s_waitcnt vmcnt(3)" ::: "memory");
      } else {
        asm volatile("s_waitcnt vmcnt(0)" ::: "memory");
      }
      __builtin_amdgcn_s_barrier();
      if (tt + 2 < NT) stage((tt + 2) % 3, tt + 2);
      short8 af[2], bf[4];
#pragma unroll
      for (int mi = 0; mi < 2; mi++)
        af[mi] = *(short8*)&As[cur * 2048 + (wr * 32 + mi * 16 + lc) * 32 + (g ^ swz) * 8];
#pragma unroll
      for (int ni = 0; ni < 4; ni++)
        bf[ni] = *(short8*)&Bs[cur * 4096 + (wc * 64 + ni * 16 + lc) * 32 + (g ^ swz) * 8];
#pragma unroll
      for (int mi = 0; mi < 2; mi++)
#pragma unroll
        for (int ni = 0; ni < 4; ni++)
          acc[mi][ni] = __builtin_amdgcn_mfma_f32_16x16x32_bf16(af[mi], bf[ni], acc[mi][ni], 0, 0, 0);
    }

#pragma unroll
    for (int mi = 0; mi < 2; mi++) {
#pragma unroll
      for (int ni = 0; ni < 4; ni++) {
#pragma unroll
        for (int r = 0; r < 4; r++) {
          const int row = m0 + wr * 32 + mi * 16 + g * 4 + r;
          const int col = n0 + wc * 64 + ni * 16 + lc;
          float v = acc[mi][ni][r] + fc_b[col] + src[(size_t)row * 1024 + col];
          attn_out[(size_t)row * 1024 + col] = v;
        }
      }
    }
  } else {
    // ================= attn_sum branch =================
    u16* Ks = (u16*)pool;                     // [64][64]
    float* tabs = (float*)(pool + 8192);      // [128]
    const int flat = xcd_swz(blockIdx.x - 512, 1024);
    const int j0 = (flat % 16) * 64;
    const int i0 = ((flat / 16) % 16) * 64;
    const int b = flat / 256;
    const int sr = t >> 3;
    const int swc = ((t & 7) ^ (sr & 7)) * 8;
    const int sc = (t & 7) * 8;
    const int rx = lc & 7;

    f32x4 acc[4] = {};

    for (int h = 0; h < 16; h++) {
      const int bh = b * 16 + h;
      __syncthreads();
      const u16* kb = k + (size_t)bh * 65536;
      *(short8*)&Ks[sr * 64 + swc]        = *(const short8*)&kb[(size_t)(j0 + sr) * 64 + sc];
      *(short8*)&Ks[(sr + 32) * 64 + swc] = *(const short8*)&kb[(size_t)(j0 + sr + 32) * 64 + sc];
      if (t < 127) tabs[t] = tab[h * 2048 + (j0 - i0 - 63 + t) + 1024] * L2E;
      __syncthreads();
      const u16* qb = q + (size_t)bh * 65536;
      short8 aq0 = *(const short8*)&qb[(size_t)(i0 + w * 16 + lc) * 64 + g * 8];
      short8 aq1 = *(const short8*)&qb[(size_t)(i0 + w * 16 + lc) * 64 + 32 + g * 8];
      f32x4 s[4] = {};
#pragma unroll
      for (int ni = 0; ni < 4; ni++) {
        short8 b0 = *(short8*)&Ks[(ni * 16 + lc) * 64 + (g ^ rx) * 8];
        short8 b1 = *(short8*)&Ks[(ni * 16 + lc) * 64 + ((4 + g) ^ rx) * 8];
        s[ni] = __builtin_amdgcn_mfma_f32_16x16x32_bf16(aq0, b0, s[ni], 0, 0, 0);
        s[ni] = __builtin_amdgcn_mfma_f32_16x16x32_bf16(aq1, b1, s[ni], 0, 0, 0);
      }
      float mm[4], li[4];
#pragma unroll
      for (int r = 0; r < 4; r++) {
        const int i = i0 + w * 16 + g * 4 + r;
        mm[r] = ml[(size_t)bh * 1024 + i];
        li[r] = 1.0f / ml[65536 + (size_t)bh * 1024 + i];
      }
#pragma unroll
      for (int ni = 0; ni < 4; ni++)
#pragma unroll
        for (int r = 0; r < 4; r++) {
          float sv = s[ni][r] + tabs[ni * 16 + lc - w * 16 - g * 4 - r + 63];
          acc[ni][r] += __builtin_amdgcn_exp2f(sv - mm[r]) * li[r];
        }
    }
#pragma unroll
    for (int ni = 0; ni < 4; ni++)
#pragma unroll
      for (int r = 0; r < 4; r++) {
        const int i = i0 + w * 16 + g * 4 + r;
        asum[((size_t)b * 1024 + i) * 1024 + j0 + ni * 16 + lc] = acc[ni][r];
      }
  }
}

// ---------- flash attention: ctx + (m,l) + fused position_bias writer ----------
__global__ __launch_bounds__(256) void attn_kernel(
    const u16* __restrict__ q, const u16* __restrict__ k,
    const u16* __restrict__ vt, const float* __restrict__ tab,
    u16* __restrict__ ctx, float* __restrict__ ml, float* __restrict__ pb) {
  const int flat = xcd_swz(blockIdx.y * 16 + blockIdx.x, 1024);
  const int bh = flat / 16;
  const int i0 = (flat % 16) * 64;
  const int h = bh & 15, b = bh >> 4;
  const int t = threadIdx.x, w = t >> 6, lane = t & 63;
  const int g = lane >> 4, lc = lane & 15;
  const int sr = t >> 3;
  const int swc = ((t & 7) ^ (sr & 7)) * 8;
  const int sc = (t & 7) * 8;

  __shared__ u16 Ks[2][64][64];
  __shared__ u16 Vts[2][64][64];
  __shared__ u16 P[4][16][64];
  __shared__ float tabs[2048];

  const u16* qb  = q + (size_t)bh * 65536;
  const u16* kb  = k + (size_t)bh * 65536;
  const u16* vtb = vt + (size_t)bh * 65536;

  // hoist full bias row for this head into LDS (UNSCALED)
  ((float4*)tabs)[t]       = ((const float4*)(tab + h * 2048))[t];
  ((float4*)tabs)[t + 256] = ((const float4*)(tab + h * 2048))[t + 256];

  const short8 aq0 = *(const short8*)&qb[(size_t)(i0 + w * 16 + lc) * 64 + g * 8];
  const short8 aq1 = *(const short8*)&qb[(size_t)(i0 + w * 16 + lc) * 64 + 32 + g * 8];

  {
    short8 ka = *(const short8*)&kb[(size_t)sr * 64 + sc];
    short8 kc = *(const short8*)&kb[(size_t)(sr + 32) * 64 + sc];
    short8 va = *(const short8*)&vtb[(size_t)sr * 1024 + sc];
    short8 vc = *(const short8*)&vtb[(size_t)(sr + 32) * 1024 + sc];
    *(short8*)&Ks[0][sr][swc]       = ka;
    *(short8*)&Ks[0][sr + 32][swc]  = kc;
    *(short8*)&Vts[0][sr][swc]      = va;
    *(short8*)&Vts[0][sr + 32][swc] = vc;
  }
  __syncthreads();

  const int rx = lc & 7;
  const int ibase = 1024 - i0 - (w * 16 + g * 4) + lc;
  float* pbrow = pb + (size_t)bh * 1048576 + (size_t)i0 * 1024 + t * 4;

  float m_r[4] = {-INFINITY, -INFINITY, -INFINITY, -INFINITY};
  float l_r[4] = {0.f, 0.f, 0.f, 0.f};
  f32x4 cacc[4] = {};

  for (int tt = 0; tt < 16; tt++) {
    const int buf = tt & 1;
    const int j0 = tt * 64;

    short8 nka, nkc, nva, nvc;
    if (tt < 15) {
      const int jn = j0 + 64;
      nka = *(const short8*)&kb[(size_t)(jn + sr) * 64 + sc];
      nkc = *(const short8*)&kb[(size_t)(jn + sr + 32) * 64 + sc];
      nva = *(const short8*)&vtb[(size_t)sr * 1024 + jn + sc];
      nvc = *(const short8*)&vtb[(size_t)(sr + 32) * 1024 + jn + sc];
    }

    f32x4 s[4] = {};
#pragma unroll
    for (int ni = 0; ni < 4; ni++) {
      short8 b0 = *(short8*)&Ks[buf][ni * 16 + lc][(g ^ rx) * 8];
      short8 b1 = *(short8*)&Ks[buf][ni * 16 + lc][((4 + g) ^ rx) * 8];
      s[ni] = __builtin_amdgcn_mfma_f32_16x16x32_bf16(aq0, b0, s[ni], 0, 0, 0);
      s[ni] = __builtin_amdgcn_mfma_f32_16x16x32_bf16(aq1, b1, s[ni], 0, 0, 0);
    }
#pragma unroll
    for (int ni = 0; ni < 4; ni++)
#pragma unroll
      for (int r = 0; r < 4; r++)
        s[ni][r] = fmaf(tabs[ibase + j0 + ni * 16 - r], L2E, s[ni][r]);

#pragma unroll
    for (int r = 0; r < 4; r++) {
      float tm = fmaxf(fmaxf(s[0][r], s[1][r]), fmaxf(s[2][r], s[3][r]));
#pragma unroll
      for (int off = 1; off < 16; off <<= 1) tm = fmaxf(tm, __shfl_xor(tm, off, 64));
      const float mn = fmaxf(m_r[r], tm);
      const float scl = __builtin_amdgcn_exp2f(m_r[r] - mn);
      float rs = 0.f;
#pragma unroll
      for (int ni = 0; ni < 4; ni++) {
        float p = __builtin_amdgcn_exp2f(s[ni][r] - mn);
        s[ni][r] = p;
        rs += p;
      }
#pragma unroll
      for (int off = 1; off < 16; off <<= 1) rs += __shfl_xor(rs, off, 64);
      l_r[r] = l_r[r] * scl + rs;
      m_r[r] = mn;
#pragma unroll
      for (int d = 0; d < 4; d++) cacc[d][r] *= scl;
    }

#pragma unroll
    for (int ni = 0; ni < 4; ni++)
#pragma unroll
      for (int r = 0; r < 4; r++) {
        const int prow = g * 4 + r;
        P[w][prow][(((ni * 2 + (lc >> 3)) ^ (prow & 7)) << 3) | (lc & 7)] = f2bf(s[ni][r]);
      }

    short8 ap0 = *(short8*)&P[w][lc][(g ^ rx) * 8];
    short8 ap1 = *(short8*)&P[w][lc][((4 + g) ^ rx) * 8];
#pragma unroll
    for (int d = 0; d < 4; d++) {
      short8 bv0 = *(short8*)&Vts[buf][d * 16 + lc][(g ^ rx) * 8];
      short8 bv1 = *(short8*)&Vts[buf][d * 16 + lc][((4 + g) ^ rx) * 8];
      cacc[d] = __builtin_amdgcn_mfma_f32_16x16x32_bf16(ap0, bv0, cacc[d], 0, 0, 0);
      cacc[d] = __builtin_amdgcn_mfma_f32_16x16x32_bf16(ap1, bv1, cacc[d], 0, 0, 0);
    }

    // ---- fused pb writer: 4 rows per iteration, values from LDS tabs ----
    {
#pragma unroll
      for (int r4 = 0; r4 < 4; r4++) {
        const int il = tt * 4 + r4;          // local row 0..63
        const int base = t * 4 - (i0 + il) + 1024;
        float4 o;
        o.x = tabs[base + 0];
        o.y = tabs[base + 1];
        o.z = tabs[base + 2];
        o.w = tabs[base + 3];
        *(float4*)&pbrow[(size_t)il * 1024] = o;
      }
    }

    if (tt < 15) {
      *(short8*)&Ks[buf ^ 1][sr][swc]       = nka;
      *(short8*)&Ks[buf ^ 1][sr + 32][swc]  = nkc;
      *(short8*)&Vts[buf ^ 1][sr][swc]      = nva;
      *(short8*)&Vts[buf ^ 1][sr + 32][swc] = nvc;
    }
    __syncthreads();
  }

  float inv[4];
#pragma unroll
  for (int r = 0; r < 4; r++) inv[r] = 1.0f / l_r[r];
#pragma unroll
  for (int d = 0; d < 4; d++)
#pragma unroll
    for (int r = 0; r < 4; r++) {
      const int pos = i0 + w * 16 + g * 4 + r;
      ctx[((size_t)b * 1024 + pos) * 1024 + h * 64 + d * 16 + lc] = f2bf(cacc[d][r] * inv[r]);
    }
  if (lc == 0) {
#pragma unroll
    for (int r = 0; r < 4; r++) {
      const int i = i0 + w * 16 + g * 4 + r;
      ml[(size_t)bh * 1024 + i] = m_r[r];
      ml[65536 + (size_t)bh * 1024 + i] = l_r[r];
    }
  }
}

// ---------- launch ----------
extern "C" void kernel_launch(void* const* d_in, const int* in_sizes, int n_in,
                              void* d_out, int out_size, void* d_ws, size_t ws_size,
                              hipStream_t stream) {
  const float* src      = (const float*)d_in[0];
  const float* ln1_w    = (const float*)d_in[2];
  const float* wq       = (const float*)d_in[3];
  const float* bq       = (const float*)d_in[4];
  const float* wk       = (const float*)d_in[5];
  const float* bk       = (const float*)d_in[6];
  const float* wv       = (const float*)d_in[7];
  const float* bv       = (const float*)d_in[8];
  const float* fc_w     = (const float*)d_in[9];
  const float* fc_b     = (const float*)d_in[10];
  const float* rel_bias = (const float*)d_in[11];
  const float* ln2_w    = (const float*)d_in[12];
  const float* wi       = (const float*)d_in[13];
  const float* wo       = (const float*)d_in[14];

  const size_t MB = 1u << 20;
  char* ws = (char*)d_ws;
  u16* wq_b   = (u16*)(ws + 0 * MB);     // wq/wk/wv contiguous = fused [3072][1024]
  u16* wk_b   = (u16*)(ws + 2 * MB);
  u16* wv_b   = (u16*)(ws + 4 * MB);
  u16* fcw_b  = (u16*)(ws + 6 * MB);
  u16* wi_b   = (u16*)(ws + 8 * MB);
  u16* wo_b   = (u16*)(ws + 16 * MB);
  u16* proj_b = (u16*)(ws + 24 * MB);   // reused as nx
  u16* q_b    = (u16*)(ws + 32 * MB);   // q/k/v contiguous, 4M u16 apart
  u16* k_b    = (u16*)(ws + 40 * MB);
  u16* v_b    = (u16*)(ws + 48 * MB);
  u16* vt_b   = (u16*)(ws + 56 * MB);
  u16* h_b    = (u16*)(ws + 32 * MB);   // aliases q/k/v/vt (dead by then)
  u16* ctx_b  = (u16*)(ws + 64 * MB);
  float* attn_out = (float*)(ws + 72 * MB);
  float* ml   = (float*)(ws + 88 * MB);
  float* tab  = (float*)(ws + 88 * MB + 512 * 1024);
  float* fb   = (float*)(ws + 90 * MB);

  float* outF = (float*)d_out;
  float* asum = outF + 4194304;
  float* pb   = outF + 8388608;

  // prep (weights/bias/tab) + first LN fused
  prep_ln<<<16524, 256, 0, stream>>>(wq, wk, wv, fc_w, wi, wo, bq, bk, bv, rel_bias,
                                     wq_b, wk_b, wv_b, fcw_b, wi_b, wo_b, fb, tab,
                                     src, ln1_w, proj_b);

  // fused QKV: 128x128 tiles, 768 blocks = exactly 3 rounds at 3/CU
  gemm_nt<0><<<dim3(24, 32), 256, 0, stream>>>(proj_b, wq_b, 4096, 3072, 1024, fb, nullptr,
                                               0.125f * L2E, nullptr, q_b);

  transpose_v<<<dim3(16, 64), 256, 0, stream>>>(v_b, vt_b);
  // attn + fused position_bias writer
  attn_kernel<<<dim3(16, 64), 256, 0, stream>>>(q_b, k_b, vt_b, tab, ctx_b, ml, pb);

  // FC + attn_sum fused (mutually independent, block-partitioned)
  fc_asum<<<1536, 256, 0, stream>>>(ctx_b, fcw_b, fc_b, src, attn_out,
                                    q_b, k_b, tab, ml, asum);

  t5_ln<<<4096, 256, 0, stream>>>(attn_out, ln2_w, 1e-6f, proj_b);

  // FFN1: 128x128 tiles
  gemm_nt<2><<<dim3(32, 32), 256, 0, stream>>>(proj_b, wi_b, 4096, 4096, 1024, nullptr, nullptr,
                                               1.0f, nullptr, h_b);
  // FFN2: 64x128 tile -> 512 blocks = 2/CU
  gemm_nt64<3><<<dim3(8, 64), 256, 0, stream>>>(h_b, wo_b, 4096, 1024, 4096, nullptr, attn_out, outF);
}